// Round 10
// baseline (12918.282 us; speedup 1.0000x reference)
//
#include <hip/hip_runtime.h>
#include <cstddef>

// Problem dims
constexpr int kB = 32;    // batch
constexpr int kT = 512;   // time steps
constexpr int kF = 513;   // input features
constexpr int kH = 512;   // hidden
constexpr int kHSlot = kH * kB;   // floats per h slot (8192)
constexpr int kD = 32;            // ring depth (power of 2)

// ---------------------------------------------------------------------------
// Agent-coherent load/store helpers (relaxed atomics -> coherence point).
// Proven for cross-XCD h exchange in rounds 7/8 (bit-exact passes).
// ---------------------------------------------------------------------------
__device__ __forceinline__ float2 aload_f2(const float* p) {
  unsigned long long u = __hip_atomic_load(
      reinterpret_cast<const unsigned long long*>(p),
      __ATOMIC_RELAXED, __HIP_MEMORY_SCOPE_AGENT);
  float2 r;
  r.x = __uint_as_float((unsigned)(u & 0xffffffffull));
  r.y = __uint_as_float((unsigned)(u >> 32));
  return r;
}
__device__ __forceinline__ float4 aload_f4(const float* p) {
  const float2 a = aload_f2(p);
  const float2 b = aload_f2(p + 2);
  return make_float4(a.x, a.y, b.x, b.y);
}
__device__ __forceinline__ float aload_f(const float* p) {
  return __hip_atomic_load(const_cast<float*>(p), __ATOMIC_RELAXED,
                           __HIP_MEMORY_SCOPE_AGENT);
}
__device__ __forceinline__ void astore_f(float* p, float v) {
  __hip_atomic_store(p, v, __ATOMIC_RELAXED, __HIP_MEMORY_SCOPE_AGENT);
}
__device__ __forceinline__ int aload_i(const int* p) {
  return __hip_atomic_load(const_cast<int*>(p), __ATOMIC_RELAXED,
                           __HIP_MEMORY_SCOPE_AGENT);
}
__device__ __forceinline__ void astore_i(int* p, int v) {
  __hip_atomic_store(p, v, __ATOMIC_RELAXED, __HIP_MEMORY_SCOPE_AGENT);
}

// ---------------------------------------------------------------------------
// Kernel 1: transpose x [B][T][F] -> xq [T][8][F][4]  (quad-blocked batch)
// ---------------------------------------------------------------------------
__global__ __launch_bounds__(256) void transpose_x(const float* __restrict__ x,
                                                   float* __restrict__ xq) {
  __shared__ float s[32][33];
  const int f0 = blockIdx.x * 32;
  const int t  = blockIdx.y;
  const int i  = threadIdx.x;
  const int lo = i & 31;
  const int g8 = i >> 5;  // 0..7
#pragma unroll
  for (int qq = 0; qq < 4; ++qq) {
    const int b = g8 * 4 + qq;
    const int f = f0 + lo;
    float v = 0.f;
    if (f < kF) v = x[((size_t)b * kT + t) * kF + f];
    s[b][lo] = v;
  }
  __syncthreads();
  const int r  = lo & 3;
  const int fl = lo >> 2;  // 0..7
#pragma unroll
  for (int it = 0; it < 4; ++it) {
    const int f = f0 + fl + 8 * it;
    if (f < kF)
      xq[((size_t)(t * 8 + g8) * kF + f) * 4 + r] = s[g8 * 4 + r][fl + 8 * it];
  }
}

// ---------------------------------------------------------------------------
// Kernel 2: persistent GRU, layer-decoupled dataflow over RING BUFFERS
// (depth kD = 32; 1 MB/layer -> ws total ~35 MB, well under proven budget;
// round 9's full-history layout needed 84 MB, the suspected overflow).
// Column math BIT-EXACT rounds 3/6/7/8. Slot s%kD holds h(s).
// Gates for layer L at step t (monotone counters, lane-parallel poll):
//   progown[*] >= t      (siblings published h(t); also own-slot WAR, D>=2)
//   progup[*]  >= t+1    (upstream h(t+1) available)           [L>0]
//   progdn[*]  >= t-kD+1 (downstream consumed slot being reused) [L<2]
// Deadlock-free (bounded pipeline, monotone counters). Graph-replay safe:
// prog + slot 0 re-zeroed per call; gates ensure slots read at step t were
// written this call.
// ---------------------------------------------------------------------------
struct GruParams {
  const float* xq;       // [T][8][513][4]
  const float* wih[3];   // [3H][KA]
  const float* whh[3];   // [3H][H]
  const float* bih[3];
  const float* bhh[3];
  float* ring[3];        // [kD][8][512][4] ring of h slots per layer
  float* out_h;          // [B*T][H]
  int* prog;             // [3][64] monotone progress (steps completed)
};

__device__ __forceinline__ void fma4(float a[4], float w, float4 v) {
  a[0] = fmaf(w, v.x, a[0]);
  a[1] = fmaf(w, v.y, a[1]);
  a[2] = fmaf(w, v.z, a[2]);
  a[3] = fmaf(w, v.w, a[3]);
}

// branchless a[s] for s in 0..3 (exact select; no value change)
__device__ __forceinline__ float pick4(const float a[4], int s) {
  const float lo = (s & 1) ? a[1] : a[0];
  const float hi = (s & 1) ? a[3] : a[2];
  return (s & 2) ? hi : lo;
}

__global__ __launch_bounds__(256, 1) void gru_seq(GruParams P) {
  // weights: segA rows (g*8+c)*520, segB at +12480; biases at 24960 (48)
  __shared__ float wlds[25008];  // 100.0 KB

  const int tid  = threadIdx.x;
  const int ks   = tid & 31;        // lane k-slice (round-3 semantics)
  const int q    = tid >> 5;        // unit = batch quad 0..7
  const int Lb   = blockIdx.x >> 6; // this block's layer 0..2
  const int rank = blockIdx.x & 63; // rank within layer-group
  const int jc0  = rank * 8;

  // ---- one-time weight + bias preload into LDS (this layer, 8 columns) ----
  {
    const float* wihL = P.wih[Lb];
    const float* whhL = P.whh[Lb];
    const int KA = (Lb == 0) ? kF : kH;
    for (int g = 0; g < 3; ++g)
      for (int c = 0; c < 8; ++c) {
        const int row = g * 8 + c;
        const float* sA = wihL + (size_t)(g * kH + jc0 + c) * KA;
        float* dA = &wlds[row * 520];
        for (int k = tid; k < KA; k += 256) dA[k] = sA[k];
        const float* sB = whhL + (size_t)(g * kH + jc0 + c) * kH;
        float* dB = &wlds[12480 + row * 520];
        for (int k = tid; k < kH; k += 256) dB[k] = sB[k];
      }
    if (tid < 48) {
      const int s2 = tid / 24;          // 0 = ih, 1 = hh
      const int g  = (tid % 24) / 8;
      const int c  = tid & 7;
      const float* src = s2 ? P.bhh[Lb] : P.bih[Lb];
      wlds[24960 + tid] = src[g * kH + jc0 + c];
    }
  }
  __syncthreads();

  float* ringown = P.ring[Lb];
  const float* ringup = (Lb > 0) ? P.ring[Lb - 1] : nullptr;
  int* progown = P.prog + Lb * 64;
  const int* progup = P.prog + (Lb - 1) * 64;
  const int* progdn = P.prog + (Lb + 1) * 64;

  for (int t = 0; t < kT; ++t) {
    // ---- dataflow gate: wave 0 polls lane-parallel, others wait ----
    if (tid < 64) {
      for (;;) {
        bool ok = (aload_i(&progown[tid]) >= t);
        if (Lb > 0) ok = ok && (aload_i(&progup[tid]) >= t + 1);
        if (Lb < 2) ok = ok && (aload_i(&progdn[tid]) >= t - (kD - 1));
        if (__ballot(ok) == ~0ull) break;
        __builtin_amdgcn_s_sleep(1);
      }
    }
    __syncthreads();

    const float* inB = ringown + (size_t)(t & (kD - 1)) * kHSlot + q * (kH * 4);

    // ---- load this lane's input quads ONCE (live across all 8 cols) ----
    float4 vA[4][4], vB[4][4];
    if (Lb == 0) {
      const float* inA = P.xq + ((size_t)t * 8 + q) * (kF * 4);
#pragma unroll
      for (int i = 0; i < 4; ++i) {
        const int k = 4 * ks + 128 * i;
#pragma unroll
        for (int m = 0; m < 4; ++m) {
          vA[i][m] = *reinterpret_cast<const float4*>(inA + (size_t)(k + m) * 4);
          vB[i][m] = aload_f4(inB + (size_t)(k + m) * 4);
        }
      }
    } else {
      const float* inA = ringup + (size_t)((t + 1) & (kD - 1)) * kHSlot + q * (kH * 4);
#pragma unroll
      for (int i = 0; i < 4; ++i) {
        const int k = 4 * ks + 128 * i;
#pragma unroll
        for (int m = 0; m < 4; ++m) {
          vA[i][m] = aload_f4(inA + (size_t)(k + m) * 4);
          vB[i][m] = aload_f4(inB + (size_t)(k + m) * 4);
        }
      }
    }
    float4 vE = make_float4(0.f, 0.f, 0.f, 0.f);
    if (Lb == 0 && ks == 0)
      vE = *reinterpret_cast<const float4*>(P.xq + ((size_t)t * 8 + q) * (kF * 4)
                                            + (size_t)512 * 4);

    // ---- 8 columns sequentially; per-column math bit-exact r3/6/7/8 ----
#pragma unroll 1
    for (int col = 0; col < 8; ++col) {
      const int jg  = jc0 + col;       // global column
      const float* wa0 = &wlds[(0 * 8 + col) * 520];
      const float* wa1 = &wlds[(1 * 8 + col) * 520];
      const float* wa2 = &wlds[(2 * 8 + col) * 520];
      const float* wb0 = &wlds[12480 + (0 * 8 + col) * 520];
      const float* wb1 = &wlds[12480 + (1 * 8 + col) * 520];
      const float* wb2 = &wlds[12480 + (2 * 8 + col) * 520];

      float aR[4]  = {0.f, 0.f, 0.f, 0.f};
      float aZ[4]  = {0.f, 0.f, 0.f, 0.f};
      float aNi[4] = {0.f, 0.f, 0.f, 0.f};
      float aNh[4] = {0.f, 0.f, 0.f, 0.f};

      // segment A: w_ih . in
#pragma unroll
      for (int i = 0; i < 4; ++i) {
        const int k = 4 * ks + 128 * i;
        const float4 w0 = *reinterpret_cast<const float4*>(wa0 + k);
        const float4 w1 = *reinterpret_cast<const float4*>(wa1 + k);
        const float4 w2 = *reinterpret_cast<const float4*>(wa2 + k);
        fma4(aR, w0.x, vA[i][0]);  fma4(aR, w0.y, vA[i][1]);
        fma4(aR, w0.z, vA[i][2]);  fma4(aR, w0.w, vA[i][3]);
        fma4(aZ, w1.x, vA[i][0]);  fma4(aZ, w1.y, vA[i][1]);
        fma4(aZ, w1.z, vA[i][2]);  fma4(aZ, w1.w, vA[i][3]);
        fma4(aNi, w2.x, vA[i][0]); fma4(aNi, w2.y, vA[i][1]);
        fma4(aNi, w2.z, vA[i][2]); fma4(aNi, w2.w, vA[i][3]);
      }
      if (Lb == 0 && ks == 0) {  // edge column k = 512 (after segA)
        fma4(aR,  wa0[512], vE);
        fma4(aZ,  wa1[512], vE);
        fma4(aNi, wa2[512], vE);
      }
      // segment B: w_hh . h_old (R,Z chain into same accumulators)
#pragma unroll
      for (int i = 0; i < 4; ++i) {
        const int k = 4 * ks + 128 * i;
        const float4 w0 = *reinterpret_cast<const float4*>(wb0 + k);
        const float4 w1 = *reinterpret_cast<const float4*>(wb1 + k);
        const float4 w2 = *reinterpret_cast<const float4*>(wb2 + k);
        fma4(aR, w0.x, vB[i][0]);  fma4(aR, w0.y, vB[i][1]);
        fma4(aR, w0.z, vB[i][2]);  fma4(aR, w0.w, vB[i][3]);
        fma4(aZ, w1.x, vB[i][0]);  fma4(aZ, w1.y, vB[i][1]);
        fma4(aZ, w1.z, vB[i][2]);  fma4(aZ, w1.w, vB[i][3]);
        fma4(aNh, w2.x, vB[i][0]); fma4(aNh, w2.y, vB[i][1]);
        fma4(aNh, w2.z, vB[i][2]); fma4(aNh, w2.w, vB[i][3]);
      }
      // butterfly all-reduce over the 32-lane half (exact round-3 order)
#pragma unroll
      for (int m = 1; m <= 16; m <<= 1) {
#pragma unroll
        for (int c2 = 0; c2 < 4; ++c2) {
          aR[c2]  += __shfl_xor(aR[c2],  m);
          aZ[c2]  += __shfl_xor(aZ[c2],  m);
          aNi[c2] += __shfl_xor(aNi[c2], m);
          aNh[c2] += __shfl_xor(aNh[c2], m);
        }
      }
      // gate combine: lanes ks<4 handle batch b = q*4 + ks
      if (ks < 4) {
        const float bi0 = wlds[24960 + 0 * 8 + col];
        const float bi1 = wlds[24960 + 1 * 8 + col];
        const float bi2 = wlds[24960 + 2 * 8 + col];
        const float bh0 = wlds[24960 + 24 + 0 * 8 + col];
        const float bh1 = wlds[24960 + 24 + 1 * 8 + col];
        const float bh2 = wlds[24960 + 24 + 2 * 8 + col];
        const float sR  = pick4(aR, ks);
        const float sZ  = pick4(aZ, ks);
        const float sNi = pick4(aNi, ks);
        const float sNh = pick4(aNh, ks);
        const float r = 1.f / (1.f + expf(-(sR + bi0 + bh0)));
        const float z = 1.f / (1.f + expf(-(sZ + bi1 + bh1)));
        const float n = tanhf(sNi + bi2 + r * (sNh + bh2));
        const float ho = aload_f(inB + jg * 4 + ks);
        const float hn = (1.f - z) * n + z * ho;
        astore_f(ringown + (size_t)((t + 1) & (kD - 1)) * kHSlot
                         + (q * kH + jg) * 4 + ks, hn);
        if (Lb == 2)
          P.out_h[((size_t)(q * 4 + ks) * kT + t) * kH + jg] = hn;
      }
    }

    // ---- publish progress: stores drained by syncthreads, then counter ----
    __syncthreads();
    if (tid == 0) astore_i(&progown[rank], t + 1);
  }
}

// ---------------------------------------------------------------------------
// Kernel 3: fused head (unchanged; bit-identical to rounds 1/3/6/7/8).
// ---------------------------------------------------------------------------
__global__ __launch_bounds__(256) void out_mask(
    const float* __restrict__ A,   // out_h [B*T][H]
    const float* __restrict__ w1, const float* __restrict__ bl1,
    const float* __restrict__ w2, const float* __restrict__ bl2,
    const float* __restrict__ x,   // [B*T][F]
    float* __restrict__ o1, float* __restrict__ o2) {
  __shared__ float As[16][68], W1s[16][68], W2s[16][68];
  const int tid = threadIdx.x;
  const int n0 = blockIdx.x * 64;
  const int m0 = blockIdx.y * 64;
  const int tn = tid & 15, tm = tid >> 4;
  const int lr = tid >> 2;
  const int lk = (tid & 3) * 4;

  float ac1[4][4], ac2[4][4];
#pragma unroll
  for (int mm = 0; mm < 4; ++mm)
#pragma unroll
    for (int nn = 0; nn < 4; ++nn) { ac1[mm][nn] = 0.f; ac2[mm][nn] = 0.f; }

  for (int k0 = 0; k0 < kH; k0 += 16) {
    const float4 av = *reinterpret_cast<const float4*>(A + (size_t)(m0 + lr) * kH + k0 + lk);
    const int fA = n0 + lr;
    float4 wv1 = make_float4(0.f, 0.f, 0.f, 0.f);
    float4 wv2 = make_float4(0.f, 0.f, 0.f, 0.f);
    if (fA < kF) {
      wv1 = *reinterpret_cast<const float4*>(w1 + (size_t)fA * kH + k0 + lk);
      wv2 = *reinterpret_cast<const float4*>(w2 + (size_t)fA * kH + k0 + lk);
    }
    __syncthreads();
    As[lk + 0][lr] = av.x;  As[lk + 1][lr] = av.y;  As[lk + 2][lr] = av.z;  As[lk + 3][lr] = av.w;
    W1s[lk + 0][lr] = wv1.x; W1s[lk + 1][lr] = wv1.y; W1s[lk + 2][lr] = wv1.z; W1s[lk + 3][lr] = wv1.w;
    W2s[lk + 0][lr] = wv2.x; W2s[lk + 1][lr] = wv2.y; W2s[lk + 2][lr] = wv2.z; W2s[lk + 3][lr] = wv2.w;
    __syncthreads();
#pragma unroll
    for (int kk = 0; kk < 16; ++kk) {
      const float4 a = *reinterpret_cast<const float4*>(&As[kk][tm * 4]);
      const float4 uu4 = *reinterpret_cast<const float4*>(&W1s[kk][tn * 4]);
      const float4 vv4 = *reinterpret_cast<const float4*>(&W2s[kk][tn * 4]);
      const float aa[4] = {a.x, a.y, a.z, a.w};
      const float uu[4] = {uu4.x, uu4.y, uu4.z, uu4.w};
      const float vv[4] = {vv4.x, vv4.y, vv4.z, vv4.w};
#pragma unroll
      for (int mm = 0; mm < 4; ++mm)
#pragma unroll
        for (int nn = 0; nn < 4; ++nn) {
          ac1[mm][nn] += aa[mm] * uu[nn];
          ac2[mm][nn] += aa[mm] * vv[nn];
        }
    }
  }
#pragma unroll
  for (int mm = 0; mm < 4; ++mm) {
    const int row = m0 + tm * 4 + mm;
#pragma unroll
    for (int nn = 0; nn < 4; ++nn) {
      const int f = n0 + tn * 4 + nn;
      if (f < kF) {
        const float s1 = fmaxf(ac1[mm][nn] + bl1[f], 0.f);
        const float s2 = fmaxf(ac2[mm][nn] + bl2[f], 0.f);
        const float inv = 1.f / (s1 + s2 + 1e-16f);
        const float xv = x[(size_t)row * kF + f];
        o1[(size_t)row * kF + f] = s1 * inv * xv;
        o2[(size_t)row * kF + f] = s2 * inv * xv;
      }
    }
  }
}

// ---------------------------------------------------------------------------
extern "C" void kernel_launch(void* const* d_in, const int* in_sizes, int n_in,
                              void* d_out, int out_size, void* d_ws, size_t ws_size,
                              hipStream_t stream) {
  const float* x = (const float*)d_in[0];
  GruParams P;
  P.wih[0] = (const float*)d_in[1];  P.whh[0] = (const float*)d_in[2];
  P.bih[0] = (const float*)d_in[3];  P.bhh[0] = (const float*)d_in[4];
  P.wih[1] = (const float*)d_in[5];  P.whh[1] = (const float*)d_in[6];
  P.bih[1] = (const float*)d_in[7];  P.bhh[1] = (const float*)d_in[8];
  P.wih[2] = (const float*)d_in[9];  P.whh[2] = (const float*)d_in[10];
  P.bih[2] = (const float*)d_in[11]; P.bhh[2] = (const float*)d_in[12];
  const float* w_l1 = (const float*)d_in[13];
  const float* b_l1 = (const float*)d_in[14];
  const float* w_l2 = (const float*)d_in[15];
  const float* b_l2 = (const float*)d_in[16];

  // ws layout: prog[3*64] ints (pad to 256) | ring0 | ring1 | ring2 | out_h
  // ring[L] = kD(32) slots x 8192 floats = 1 MB each; out_h 32 MB.
  // Total ~35.2 MB (round 9's 84 MB full-history layout suspected overflow).
  int* prog = (int*)d_ws;
  float* ws = (float*)d_ws + 256;
  const size_t ringSz = (size_t)kD * kHSlot;
  for (int l = 0; l < 3; ++l) {
    P.ring[l] = ws;
    ws += ringSz;
  }
  float* out_h = ws;                                     // [B*T][H]
  P.prog = prog;
  P.out_h = out_h;

  // xq lives in the o1 half of d_out (dead until out_mask overwrites it):
  // [T][8][513][4] = 8,404,992 floats = exactly o1's size.
  float* o1 = (float*)d_out;
  float* o2 = o1 + (size_t)kB * kT * kF;
  float* xq = o1;
  P.xq = xq;

  // zero prog counters and slot 0 (= h(0) = 0) of each ring
  hipMemsetAsync(prog, 0, 256 * sizeof(int), stream);
  hipMemsetAsync(P.ring[0], 0, kHSlot * sizeof(float), stream);
  hipMemsetAsync(P.ring[1], 0, kHSlot * sizeof(float), stream);
  hipMemsetAsync(P.ring[2], 0, kHSlot * sizeof(float), stream);

  transpose_x<<<dim3(17, kT), 256, 0, stream>>>(x, xq);

  void* args[] = { (void*)&P };
  hipLaunchCooperativeKernel((void*)gru_seq, dim3(192), dim3(256), args, 0u, stream);

  out_mask<<<dim3(9, 256), 256, 0, stream>>>(out_h, w_l1, b_l1, w_l2, b_l2, x, o1, o2);
}

// Round 11
// 11371.372 us; speedup vs baseline: 1.1360x; 1.1360x over previous
//
#include <hip/hip_runtime.h>
#include <cstddef>

// Problem dims
constexpr int kB = 32;    // batch
constexpr int kT = 512;   // time steps
constexpr int kF = 513;   // input features
constexpr int kH = 512;   // hidden
constexpr int kHSlot = kH * kB;   // floats per h slot (16384 = 64 KB)
constexpr int kD = 64;            // ring depth (power of 2)

// ---------------------------------------------------------------------------
// Agent-coherent helpers. sc-STORES publish h to the coherence point (L3);
// sc-loads remain ONLY for the tiny prog counters (re-read same address ->
// must bypass stale L2). Bulk h READS are now PLAIN cached loads: correct
// because ring lines are write-once per 64-step generation and every block
// issues a __threadfence() (L1/L2 invalidate; r6-proven mechanism, r7-proven
// <1us cost) at generation crossings before first-touching new-gen lines.
// ---------------------------------------------------------------------------
__device__ __forceinline__ void astore_f(float* p, float v) {
  __hip_atomic_store(p, v, __ATOMIC_RELAXED, __HIP_MEMORY_SCOPE_AGENT);
}
__device__ __forceinline__ int aload_i(const int* p) {
  return __hip_atomic_load(const_cast<int*>(p), __ATOMIC_RELAXED,
                           __HIP_MEMORY_SCOPE_AGENT);
}
__device__ __forceinline__ void astore_i(int* p, int v) {
  __hip_atomic_store(p, v, __ATOMIC_RELAXED, __HIP_MEMORY_SCOPE_AGENT);
}

// ---------------------------------------------------------------------------
// Kernel 1: transpose x [B][T][F] -> xq [T][8][F][4]  (quad-blocked batch)
// ---------------------------------------------------------------------------
__global__ __launch_bounds__(256) void transpose_x(const float* __restrict__ x,
                                                   float* __restrict__ xq) {
  __shared__ float s[32][33];
  const int f0 = blockIdx.x * 32;
  const int t  = blockIdx.y;
  const int i  = threadIdx.x;
  const int lo = i & 31;
  const int g8 = i >> 5;  // 0..7
#pragma unroll
  for (int qq = 0; qq < 4; ++qq) {
    const int b = g8 * 4 + qq;
    const int f = f0 + lo;
    float v = 0.f;
    if (f < kF) v = x[((size_t)b * kT + t) * kF + f];
    s[b][lo] = v;
  }
  __syncthreads();
  const int r  = lo & 3;
  const int fl = lo >> 2;  // 0..7
#pragma unroll
  for (int it = 0; it < 4; ++it) {
    const int f = f0 + fl + 8 * it;
    if (f < kF)
      xq[((size_t)(t * 8 + g8) * kF + f) * 4 + r] = s[g8 * 4 + r][fl + 8 * it];
  }
}

// ---------------------------------------------------------------------------
// Kernel 2: persistent GRU, layer-decoupled dataflow over depth-64 rings.
// Column math BIT-EXACT rounds 3/6/7/8/10. Changes vs round 10 (perf only):
//  * h READS -> plain cached float4 loads (L1/L2 hits; coherence-point
//    traffic drops 24 MB/step -> ~1 MB/step)
//  * generation-crossing __threadfence() (tid0, t%64 in {0,63}; 16x/run)
//    guarantees no stale-generation L2 lines (intra-layer lockstep <=1 step
//    means co-resident re-caching is always current-generation values)
//  * rings live in d_out (12 MB, dead before out_mask); xq/out_h in ws
//    (65.7 MB total = round-1-proven footprint)
// h WRITES stay sc-stores (publish to L3, which plain L2-misses read).
// ---------------------------------------------------------------------------
struct GruParams {
  const float* xq;       // [T][8][513][4]
  const float* wih[3];   // [3H][KA]
  const float* whh[3];   // [3H][H]
  const float* bih[3];
  const float* bhh[3];
  float* ring[3];        // [kD][8][512][4] ring of h slots per layer
  float* out_h;          // [B*T][H]
  int* prog;             // [3][64] monotone progress (steps completed)
};

__device__ __forceinline__ void fma4(float a[4], float w, float4 v) {
  a[0] = fmaf(w, v.x, a[0]);
  a[1] = fmaf(w, v.y, a[1]);
  a[2] = fmaf(w, v.z, a[2]);
  a[3] = fmaf(w, v.w, a[3]);
}

// branchless a[s] for s in 0..3 (exact select; no value change)
__device__ __forceinline__ float pick4(const float a[4], int s) {
  const float lo = (s & 1) ? a[1] : a[0];
  const float hi = (s & 1) ? a[3] : a[2];
  return (s & 2) ? hi : lo;
}

__global__ __launch_bounds__(256, 1) void gru_seq(GruParams P) {
  // weights: segA rows (g*8+c)*520, segB at +12480; biases at 24960 (48)
  __shared__ float wlds[25008];  // 100.0 KB

  const int tid  = threadIdx.x;
  const int ks   = tid & 31;        // lane k-slice (round-3 semantics)
  const int q    = tid >> 5;        // unit = batch quad 0..7
  const int Lb   = blockIdx.x >> 6; // this block's layer 0..2
  const int rank = blockIdx.x & 63; // rank within layer-group
  const int jc0  = rank * 8;

  // ---- one-time weight + bias preload into LDS (this layer, 8 columns) ----
  {
    const float* wihL = P.wih[Lb];
    const float* whhL = P.whh[Lb];
    const int KA = (Lb == 0) ? kF : kH;
    for (int g = 0; g < 3; ++g)
      for (int c = 0; c < 8; ++c) {
        const int row = g * 8 + c;
        const float* sA = wihL + (size_t)(g * kH + jc0 + c) * KA;
        float* dA = &wlds[row * 520];
        for (int k = tid; k < KA; k += 256) dA[k] = sA[k];
        const float* sB = whhL + (size_t)(g * kH + jc0 + c) * kH;
        float* dB = &wlds[12480 + row * 520];
        for (int k = tid; k < kH; k += 256) dB[k] = sB[k];
      }
    if (tid < 48) {
      const int s2 = tid / 24;          // 0 = ih, 1 = hh
      const int g  = (tid % 24) / 8;
      const int c  = tid & 7;
      const float* src = s2 ? P.bhh[Lb] : P.bih[Lb];
      wlds[24960 + tid] = src[g * kH + jc0 + c];
    }
  }
  __syncthreads();

  float* ringown = P.ring[Lb];
  const float* ringup = (Lb > 0) ? P.ring[Lb - 1] : nullptr;
  int* progown = P.prog + Lb * 64;
  const int* progup = P.prog + (Lb - 1) * 64;
  const int* progdn = P.prog + (Lb + 1) * 64;

  for (int t = 0; t < kT; ++t) {
    // ---- dataflow gate: wave 0 polls lane-parallel (sc loads), rest wait ----
    if (tid < 64) {
      for (;;) {
        bool ok = (aload_i(&progown[tid]) >= t);
        if (Lb > 0) ok = ok && (aload_i(&progup[tid]) >= t + 1);
        if (Lb < 2) ok = ok && (aload_i(&progdn[tid]) >= t - (kD - 1));
        if (__ballot(ok) == ~0ull) break;
        __builtin_amdgcn_s_sleep(1);
      }
    }
    // ---- generation-crossing acquire: invalidate L1/L2 so the plain loads
    // below refetch fresh lines. inB slot t wraps at t%64==0; upstream inA
    // slot t+1 wraps at t%64==63. Executed 16x per run per block.
    if (tid == 0) {
      const int tm = t & (kD - 1);
      if (tm == 0 || tm == kD - 1) __threadfence();
    }
    __syncthreads();

    const float* inB = ringown + (size_t)(t & (kD - 1)) * kHSlot + q * (kH * 4);

    // ---- load this lane's input quads ONCE (plain, cached; live 8 cols) ----
    float4 vA[4][4], vB[4][4];
    if (Lb == 0) {
      const float* inA = P.xq + ((size_t)t * 8 + q) * (kF * 4);
#pragma unroll
      for (int i = 0; i < 4; ++i) {
        const int k = 4 * ks + 128 * i;
#pragma unroll
        for (int m = 0; m < 4; ++m) {
          vA[i][m] = *reinterpret_cast<const float4*>(inA + (size_t)(k + m) * 4);
          vB[i][m] = *reinterpret_cast<const float4*>(inB + (size_t)(k + m) * 4);
        }
      }
    } else {
      const float* inA = ringup + (size_t)((t + 1) & (kD - 1)) * kHSlot + q * (kH * 4);
#pragma unroll
      for (int i = 0; i < 4; ++i) {
        const int k = 4 * ks + 128 * i;
#pragma unroll
        for (int m = 0; m < 4; ++m) {
          vA[i][m] = *reinterpret_cast<const float4*>(inA + (size_t)(k + m) * 4);
          vB[i][m] = *reinterpret_cast<const float4*>(inB + (size_t)(k + m) * 4);
        }
      }
    }
    float4 vE = make_float4(0.f, 0.f, 0.f, 0.f);
    if (Lb == 0 && ks == 0)
      vE = *reinterpret_cast<const float4*>(P.xq + ((size_t)t * 8 + q) * (kF * 4)
                                            + (size_t)512 * 4);

    // ---- 8 columns sequentially; per-column math bit-exact r3/6/7/8/10 ----
#pragma unroll 1
    for (int col = 0; col < 8; ++col) {
      const int jg  = jc0 + col;       // global column
      const float* wa0 = &wlds[(0 * 8 + col) * 520];
      const float* wa1 = &wlds[(1 * 8 + col) * 520];
      const float* wa2 = &wlds[(2 * 8 + col) * 520];
      const float* wb0 = &wlds[12480 + (0 * 8 + col) * 520];
      const float* wb1 = &wlds[12480 + (1 * 8 + col) * 520];
      const float* wb2 = &wlds[12480 + (2 * 8 + col) * 520];

      float aR[4]  = {0.f, 0.f, 0.f, 0.f};
      float aZ[4]  = {0.f, 0.f, 0.f, 0.f};
      float aNi[4] = {0.f, 0.f, 0.f, 0.f};
      float aNh[4] = {0.f, 0.f, 0.f, 0.f};

      // segment A: w_ih . in
#pragma unroll
      for (int i = 0; i < 4; ++i) {
        const int k = 4 * ks + 128 * i;
        const float4 w0 = *reinterpret_cast<const float4*>(wa0 + k);
        const float4 w1 = *reinterpret_cast<const float4*>(wa1 + k);
        const float4 w2 = *reinterpret_cast<const float4*>(wa2 + k);
        fma4(aR, w0.x, vA[i][0]);  fma4(aR, w0.y, vA[i][1]);
        fma4(aR, w0.z, vA[i][2]);  fma4(aR, w0.w, vA[i][3]);
        fma4(aZ, w1.x, vA[i][0]);  fma4(aZ, w1.y, vA[i][1]);
        fma4(aZ, w1.z, vA[i][2]);  fma4(aZ, w1.w, vA[i][3]);
        fma4(aNi, w2.x, vA[i][0]); fma4(aNi, w2.y, vA[i][1]);
        fma4(aNi, w2.z, vA[i][2]); fma4(aNi, w2.w, vA[i][3]);
      }
      if (Lb == 0 && ks == 0) {  // edge column k = 512 (after segA)
        fma4(aR,  wa0[512], vE);
        fma4(aZ,  wa1[512], vE);
        fma4(aNi, wa2[512], vE);
      }
      // segment B: w_hh . h_old (R,Z chain into same accumulators)
#pragma unroll
      for (int i = 0; i < 4; ++i) {
        const int k = 4 * ks + 128 * i;
        const float4 w0 = *reinterpret_cast<const float4*>(wb0 + k);
        const float4 w1 = *reinterpret_cast<const float4*>(wb1 + k);
        const float4 w2 = *reinterpret_cast<const float4*>(wb2 + k);
        fma4(aR, w0.x, vB[i][0]);  fma4(aR, w0.y, vB[i][1]);
        fma4(aR, w0.z, vB[i][2]);  fma4(aR, w0.w, vB[i][3]);
        fma4(aZ, w1.x, vB[i][0]);  fma4(aZ, w1.y, vB[i][1]);
        fma4(aZ, w1.z, vB[i][2]);  fma4(aZ, w1.w, vB[i][3]);
        fma4(aNh, w2.x, vB[i][0]); fma4(aNh, w2.y, vB[i][1]);
        fma4(aNh, w2.z, vB[i][2]); fma4(aNh, w2.w, vB[i][3]);
      }
      // butterfly all-reduce over the 32-lane half (exact round-3 order)
#pragma unroll
      for (int m = 1; m <= 16; m <<= 1) {
#pragma unroll
        for (int c2 = 0; c2 < 4; ++c2) {
          aR[c2]  += __shfl_xor(aR[c2],  m);
          aZ[c2]  += __shfl_xor(aZ[c2],  m);
          aNi[c2] += __shfl_xor(aNi[c2], m);
          aNh[c2] += __shfl_xor(aNh[c2], m);
        }
      }
      // gate combine: lanes ks<4 handle batch b = q*4 + ks
      if (ks < 4) {
        const float bi0 = wlds[24960 + 0 * 8 + col];
        const float bi1 = wlds[24960 + 1 * 8 + col];
        const float bi2 = wlds[24960 + 2 * 8 + col];
        const float bh0 = wlds[24960 + 24 + 0 * 8 + col];
        const float bh1 = wlds[24960 + 24 + 1 * 8 + col];
        const float bh2 = wlds[24960 + 24 + 2 * 8 + col];
        const float sR  = pick4(aR, ks);
        const float sZ  = pick4(aZ, ks);
        const float sNi = pick4(aNi, ks);
        const float sNh = pick4(aNh, ks);
        const float r = 1.f / (1.f + expf(-(sR + bi0 + bh0)));
        const float z = 1.f / (1.f + expf(-(sZ + bi1 + bh1)));
        const float n = tanhf(sNi + bi2 + r * (sNh + bh2));
        const float ho = inB[jg * 4 + ks];   // plain: line already L1-hot
        const float hn = (1.f - z) * n + z * ho;
        astore_f(ringown + (size_t)((t + 1) & (kD - 1)) * kHSlot
                         + (q * kH + jg) * 4 + ks, hn);
        if (Lb == 2)
          P.out_h[((size_t)(q * 4 + ks) * kT + t) * kH + jg] = hn;
      }
    }

    // ---- publish: syncthreads drains sc-stores (vmcnt 0), then counter ----
    __syncthreads();
    if (tid == 0) astore_i(&progown[rank], t + 1);
  }
}

// ---------------------------------------------------------------------------
// Kernel 3: fused head (unchanged; bit-identical to rounds 1/3/6/7/8/10).
// ---------------------------------------------------------------------------
__global__ __launch_bounds__(256) void out_mask(
    const float* __restrict__ A,   // out_h [B*T][H]
    const float* __restrict__ w1, const float* __restrict__ bl1,
    const float* __restrict__ w2, const float* __restrict__ bl2,
    const float* __restrict__ x,   // [B*T][F]
    float* __restrict__ o1, float* __restrict__ o2) {
  __shared__ float As[16][68], W1s[16][68], W2s[16][68];
  const int tid = threadIdx.x;
  const int n0 = blockIdx.x * 64;
  const int m0 = blockIdx.y * 64;
  const int tn = tid & 15, tm = tid >> 4;
  const int lr = tid >> 2;
  const int lk = (tid & 3) * 4;

  float ac1[4][4], ac2[4][4];
#pragma unroll
  for (int mm = 0; mm < 4; ++mm)
#pragma unroll
    for (int nn = 0; nn < 4; ++nn) { ac1[mm][nn] = 0.f; ac2[mm][nn] = 0.f; }

  for (int k0 = 0; k0 < kH; k0 += 16) {
    const float4 av = *reinterpret_cast<const float4*>(A + (size_t)(m0 + lr) * kH + k0 + lk);
    const int fA = n0 + lr;
    float4 wv1 = make_float4(0.f, 0.f, 0.f, 0.f);
    float4 wv2 = make_float4(0.f, 0.f, 0.f, 0.f);
    if (fA < kF) {
      wv1 = *reinterpret_cast<const float4*>(w1 + (size_t)fA * kH + k0 + lk);
      wv2 = *reinterpret_cast<const float4*>(w2 + (size_t)fA * kH + k0 + lk);
    }
    __syncthreads();
    As[lk + 0][lr] = av.x;  As[lk + 1][lr] = av.y;  As[lk + 2][lr] = av.z;  As[lk + 3][lr] = av.w;
    W1s[lk + 0][lr] = wv1.x; W1s[lk + 1][lr] = wv1.y; W1s[lk + 2][lr] = wv1.z; W1s[lk + 3][lr] = wv1.w;
    W2s[lk + 0][lr] = wv2.x; W2s[lk + 1][lr] = wv2.y; W2s[lk + 2][lr] = wv2.z; W2s[lk + 3][lr] = wv2.w;
    __syncthreads();
#pragma unroll
    for (int kk = 0; kk < 16; ++kk) {
      const float4 a = *reinterpret_cast<const float4*>(&As[kk][tm * 4]);
      const float4 uu4 = *reinterpret_cast<const float4*>(&W1s[kk][tn * 4]);
      const float4 vv4 = *reinterpret_cast<const float4*>(&W2s[kk][tn * 4]);
      const float aa[4] = {a.x, a.y, a.z, a.w};
      const float uu[4] = {uu4.x, uu4.y, uu4.z, uu4.w};
      const float vv[4] = {vv4.x, vv4.y, vv4.z, vv4.w};
#pragma unroll
      for (int mm = 0; mm < 4; ++mm)
#pragma unroll
        for (int nn = 0; nn < 4; ++nn) {
          ac1[mm][nn] += aa[mm] * uu[nn];
          ac2[mm][nn] += aa[mm] * vv[nn];
        }
    }
  }
#pragma unroll
  for (int mm = 0; mm < 4; ++mm) {
    const int row = m0 + tm * 4 + mm;
#pragma unroll
    for (int nn = 0; nn < 4; ++nn) {
      const int f = n0 + tn * 4 + nn;
      if (f < kF) {
        const float s1 = fmaxf(ac1[mm][nn] + bl1[f], 0.f);
        const float s2 = fmaxf(ac2[mm][nn] + bl2[f], 0.f);
        const float inv = 1.f / (s1 + s2 + 1e-16f);
        const float xv = x[(size_t)row * kF + f];
        o1[(size_t)row * kF + f] = s1 * inv * xv;
        o2[(size_t)row * kF + f] = s2 * inv * xv;
      }
    }
  }
}

// ---------------------------------------------------------------------------
extern "C" void kernel_launch(void* const* d_in, const int* in_sizes, int n_in,
                              void* d_out, int out_size, void* d_ws, size_t ws_size,
                              hipStream_t stream) {
  const float* x = (const float*)d_in[0];
  GruParams P;
  P.wih[0] = (const float*)d_in[1];  P.whh[0] = (const float*)d_in[2];
  P.bih[0] = (const float*)d_in[3];  P.bhh[0] = (const float*)d_in[4];
  P.wih[1] = (const float*)d_in[5];  P.whh[1] = (const float*)d_in[6];
  P.bih[1] = (const float*)d_in[7];  P.bhh[1] = (const float*)d_in[8];
  P.wih[2] = (const float*)d_in[9];  P.whh[2] = (const float*)d_in[10];
  P.bih[2] = (const float*)d_in[11]; P.bhh[2] = (const float*)d_in[12];
  const float* w_l1 = (const float*)d_in[13];
  const float* b_l1 = (const float*)d_in[14];
  const float* w_l2 = (const float*)d_in[15];
  const float* b_l2 = (const float*)d_in[16];

  // ws layout (round-1-proven ~66 MB footprint): xq | out_h | prog
  float* xq = (float*)d_ws;                              // 8,404,992 floats
  float* out_h = xq + (size_t)kT * 8 * kF * 4;           // 8,388,608 floats
  int* prog = (int*)(out_h + (size_t)kB * kT * kH);      // 256 ints
  P.xq = xq;
  P.out_h = out_h;
  P.prog = prog;

  // rings live in d_out's o1 region (12 MB of 33.6 MB; dead before out_mask
  // overwrites o1). o1/o2 are the final outputs.
  float* o1 = (float*)d_out;
  float* o2 = o1 + (size_t)kB * kT * kF;
  const size_t ringSz = (size_t)kD * kHSlot;             // 4 MB each
  for (int l = 0; l < 3; ++l) P.ring[l] = o1 + (size_t)l * ringSz;

  // zero prog counters and slot 0 (= h(0) = 0) of each ring (every call)
  hipMemsetAsync(prog, 0, 256 * sizeof(int), stream);
  hipMemsetAsync(P.ring[0], 0, kHSlot * sizeof(float), stream);
  hipMemsetAsync(P.ring[1], 0, kHSlot * sizeof(float), stream);
  hipMemsetAsync(P.ring[2], 0, kHSlot * sizeof(float), stream);

  transpose_x<<<dim3(17, kT), 256, 0, stream>>>(x, xq);

  void* args[] = { (void*)&P };
  hipLaunchCooperativeKernel((void*)gru_seq, dim3(192), dim3(256), args, 0u, stream);

  out_mask<<<dim3(9, 256), 256, 0, stream>>>(out_h, w_l1, b_l1, w_l2, b_l2, x, o1, o2);
}

// Round 12
// 10688.415 us; speedup vs baseline: 1.2086x; 1.0639x over previous
//
#include <hip/hip_runtime.h>
#include <cstddef>

// Problem dims
constexpr int kB = 32;    // batch
constexpr int kT = 512;   // time steps
constexpr int kF = 513;   // input features
constexpr int kH = 512;   // hidden
constexpr int kHSlot = kH * kB;   // floats per h slot (16384 = 64 KB)
constexpr int kD = 64;            // ring depth (power of 2)

// ---------------------------------------------------------------------------
// Agent-coherent helpers (relaxed atomics -> coherence point). sc-stores
// publish h/counters; sc-loads only for counters. Bulk h reads are plain
// cached loads guarded by the per-generation __threadfence (r11-proven).
// ---------------------------------------------------------------------------
__device__ __forceinline__ void astore_f(float* p, float v) {
  __hip_atomic_store(p, v, __ATOMIC_RELAXED, __HIP_MEMORY_SCOPE_AGENT);
}
__device__ __forceinline__ int aload_i(const int* p) {
  return __hip_atomic_load(const_cast<int*>(p), __ATOMIC_RELAXED,
                           __HIP_MEMORY_SCOPE_AGENT);
}
__device__ __forceinline__ void astore_i(int* p, int v) {
  __hip_atomic_store(p, v, __ATOMIC_RELAXED, __HIP_MEMORY_SCOPE_AGENT);
}

// ---------------------------------------------------------------------------
// Kernel 1: transpose x [B][T][F] -> xq [T][8][F][4]  (quad-blocked batch)
// ---------------------------------------------------------------------------
__global__ __launch_bounds__(256) void transpose_x(const float* __restrict__ x,
                                                   float* __restrict__ xq) {
  __shared__ float s[32][33];
  const int f0 = blockIdx.x * 32;
  const int t  = blockIdx.y;
  const int i  = threadIdx.x;
  const int lo = i & 31;
  const int g8 = i >> 5;  // 0..7
#pragma unroll
  for (int qq = 0; qq < 4; ++qq) {
    const int b = g8 * 4 + qq;
    const int f = f0 + lo;
    float v = 0.f;
    if (f < kF) v = x[((size_t)b * kT + t) * kF + f];
    s[b][lo] = v;
  }
  __syncthreads();
  const int r  = lo & 3;
  const int fl = lo >> 2;  // 0..7
#pragma unroll
  for (int it = 0; it < 4; ++it) {
    const int f = f0 + fl + 8 * it;
    if (f < kF)
      xq[((size_t)(t * 8 + g8) * kF + f) * 4 + r] = s[g8 * 4 + r][fl + 8 * it];
  }
}

// ---------------------------------------------------------------------------
// Kernel 2: persistent GRU, layer-decoupled dataflow over depth-64 rings.
// Column math BIT-EXACT rounds 3/6/7/8/10/11. Change vs round 11 (gates
// only): counter-congestion fix. 192 compute blocks no longer sweep 64 raw
// counters each; 3 DEDICATED AGGREGATOR blocks (192..194, never compute)
// sweep their layer's raw counters and publish one line-isolated lall[L]
// word. Compute blocks poll only 3 lall words (3 lanes, 3 line-reads/iter)
// -> ~100x less load on the hot lines; publishes land uncontended.
// Gate semantics (equivalent to r11):
//   lall[L]   >= t      : all siblings completed t-1 (slot t complete)
//   lall[L-1] >= t+1    : upstream h(t+1) complete                  [L>0]
//   lall[L+1] >= t-63   : downstream done with slot being rewritten [L<2]
// ---------------------------------------------------------------------------
struct GruParams {
  const float* xq;       // [T][8][513][4]
  const float* wih[3];   // [3H][KA]
  const float* whh[3];   // [3H][H]
  const float* bih[3];
  const float* bhh[3];
  float* ring[3];        // [kD][8][512][4] ring of h slots per layer
  float* out_h;          // [B*T][H]
  int* prog;             // [3][64] monotone per-block progress
  int* lall;             // [3] stride-32 line-isolated layer progress
};

__device__ __forceinline__ void fma4(float a[4], float w, float4 v) {
  a[0] = fmaf(w, v.x, a[0]);
  a[1] = fmaf(w, v.y, a[1]);
  a[2] = fmaf(w, v.z, a[2]);
  a[3] = fmaf(w, v.w, a[3]);
}

// branchless a[s] for s in 0..3 (exact select; no value change)
__device__ __forceinline__ float pick4(const float a[4], int s) {
  const float lo = (s & 1) ? a[1] : a[0];
  const float hi = (s & 1) ? a[3] : a[2];
  return (s & 2) ? hi : lo;
}

__global__ __launch_bounds__(256, 1) void gru_seq(GruParams P) {
  // weights: segA rows (g*8+c)*520, segB at +12480; biases at 24960 (48)
  __shared__ float wlds[25008];  // 100.0 KB

  const int tid = threadIdx.x;

  // ---- dedicated aggregator blocks: sweep raw counters, publish lall ----
  if (blockIdx.x >= 192) {
    const int L = blockIdx.x - 192;
    const int* cnt = P.prog + L * 64;
    if (tid < 64) {
      for (int t = 1; t <= kT; ++t) {
        for (;;) {
          const bool ok = (aload_i(&cnt[tid]) >= t);
          if (__ballot(ok) == ~0ull) break;
          __builtin_amdgcn_s_sleep(2);
        }
        if (tid == 0) astore_i(&P.lall[L * 32], t);
      }
    }
    return;
  }

  const int ks   = tid & 31;        // lane k-slice (round-3 semantics)
  const int q    = tid >> 5;        // unit = batch quad 0..7
  const int Lb   = blockIdx.x >> 6; // this block's layer 0..2
  const int rank = blockIdx.x & 63; // rank within layer-group
  const int jc0  = rank * 8;

  // ---- one-time weight + bias preload into LDS (this layer, 8 columns) ----
  {
    const float* wihL = P.wih[Lb];
    const float* whhL = P.whh[Lb];
    const int KA = (Lb == 0) ? kF : kH;
    for (int g = 0; g < 3; ++g)
      for (int c = 0; c < 8; ++c) {
        const int row = g * 8 + c;
        const float* sA = wihL + (size_t)(g * kH + jc0 + c) * KA;
        float* dA = &wlds[row * 520];
        for (int k = tid; k < KA; k += 256) dA[k] = sA[k];
        const float* sB = whhL + (size_t)(g * kH + jc0 + c) * kH;
        float* dB = &wlds[12480 + row * 520];
        for (int k = tid; k < kH; k += 256) dB[k] = sB[k];
      }
    if (tid < 48) {
      const int s2 = tid / 24;          // 0 = ih, 1 = hh
      const int g  = (tid % 24) / 8;
      const int c  = tid & 7;
      const float* src = s2 ? P.bhh[Lb] : P.bih[Lb];
      wlds[24960 + tid] = src[g * kH + jc0 + c];
    }
  }
  __syncthreads();

  float* ringown = P.ring[Lb];
  const float* ringup = (Lb > 0) ? P.ring[Lb - 1] : nullptr;
  int* progown = P.prog + Lb * 64;

  for (int t = 0; t < kT; ++t) {
    // ---- dataflow gate: 3 lanes poll 3 line-isolated lall words ----
    if (tid < 64) {
      for (;;) {
        bool ok = true;
        if (tid == 0) ok = (aload_i(&P.lall[Lb * 32]) >= t);
        else if (tid == 1 && Lb > 0) ok = (aload_i(&P.lall[(Lb - 1) * 32]) >= t + 1);
        else if (tid == 2 && Lb < 2) ok = (aload_i(&P.lall[(Lb + 1) * 32]) >= t - (kD - 1));
        if (__ballot(ok) == ~0ull) break;
        __builtin_amdgcn_s_sleep(2);
      }
    }
    // ---- generation-crossing acquire (r11-proven): invalidate L1/L2 so
    // plain loads refetch fresh ring lines; 16x per run per block.
    if (tid == 0) {
      const int tm = t & (kD - 1);
      if (tm == 0 || tm == kD - 1) __threadfence();
    }
    __syncthreads();

    const float* inB = ringown + (size_t)(t & (kD - 1)) * kHSlot + q * (kH * 4);

    // ---- load this lane's input quads ONCE (plain, cached; live 8 cols) ----
    float4 vA[4][4], vB[4][4];
    if (Lb == 0) {
      const float* inA = P.xq + ((size_t)t * 8 + q) * (kF * 4);
#pragma unroll
      for (int i = 0; i < 4; ++i) {
        const int k = 4 * ks + 128 * i;
#pragma unroll
        for (int m = 0; m < 4; ++m) {
          vA[i][m] = *reinterpret_cast<const float4*>(inA + (size_t)(k + m) * 4);
          vB[i][m] = *reinterpret_cast<const float4*>(inB + (size_t)(k + m) * 4);
        }
      }
    } else {
      const float* inA = ringup + (size_t)((t + 1) & (kD - 1)) * kHSlot + q * (kH * 4);
#pragma unroll
      for (int i = 0; i < 4; ++i) {
        const int k = 4 * ks + 128 * i;
#pragma unroll
        for (int m = 0; m < 4; ++m) {
          vA[i][m] = *reinterpret_cast<const float4*>(inA + (size_t)(k + m) * 4);
          vB[i][m] = *reinterpret_cast<const float4*>(inB + (size_t)(k + m) * 4);
        }
      }
    }
    float4 vE = make_float4(0.f, 0.f, 0.f, 0.f);
    if (Lb == 0 && ks == 0)
      vE = *reinterpret_cast<const float4*>(P.xq + ((size_t)t * 8 + q) * (kF * 4)
                                            + (size_t)512 * 4);

    // ---- 8 columns sequentially; per-column math bit-exact r3..r11 ----
#pragma unroll 1
    for (int col = 0; col < 8; ++col) {
      const int jg  = jc0 + col;       // global column
      const float* wa0 = &wlds[(0 * 8 + col) * 520];
      const float* wa1 = &wlds[(1 * 8 + col) * 520];
      const float* wa2 = &wlds[(2 * 8 + col) * 520];
      const float* wb0 = &wlds[12480 + (0 * 8 + col) * 520];
      const float* wb1 = &wlds[12480 + (1 * 8 + col) * 520];
      const float* wb2 = &wlds[12480 + (2 * 8 + col) * 520];

      float aR[4]  = {0.f, 0.f, 0.f, 0.f};
      float aZ[4]  = {0.f, 0.f, 0.f, 0.f};
      float aNi[4] = {0.f, 0.f, 0.f, 0.f};
      float aNh[4] = {0.f, 0.f, 0.f, 0.f};

      // segment A: w_ih . in
#pragma unroll
      for (int i = 0; i < 4; ++i) {
        const int k = 4 * ks + 128 * i;
        const float4 w0 = *reinterpret_cast<const float4*>(wa0 + k);
        const float4 w1 = *reinterpret_cast<const float4*>(wa1 + k);
        const float4 w2 = *reinterpret_cast<const float4*>(wa2 + k);
        fma4(aR, w0.x, vA[i][0]);  fma4(aR, w0.y, vA[i][1]);
        fma4(aR, w0.z, vA[i][2]);  fma4(aR, w0.w, vA[i][3]);
        fma4(aZ, w1.x, vA[i][0]);  fma4(aZ, w1.y, vA[i][1]);
        fma4(aZ, w1.z, vA[i][2]);  fma4(aZ, w1.w, vA[i][3]);
        fma4(aNi, w2.x, vA[i][0]); fma4(aNi, w2.y, vA[i][1]);
        fma4(aNi, w2.z, vA[i][2]); fma4(aNi, w2.w, vA[i][3]);
      }
      if (Lb == 0 && ks == 0) {  // edge column k = 512 (after segA)
        fma4(aR,  wa0[512], vE);
        fma4(aZ,  wa1[512], vE);
        fma4(aNi, wa2[512], vE);
      }
      // segment B: w_hh . h_old (R,Z chain into same accumulators)
#pragma unroll
      for (int i = 0; i < 4; ++i) {
        const int k = 4 * ks + 128 * i;
        const float4 w0 = *reinterpret_cast<const float4*>(wb0 + k);
        const float4 w1 = *reinterpret_cast<const float4*>(wb1 + k);
        const float4 w2 = *reinterpret_cast<const float4*>(wb2 + k);
        fma4(aR, w0.x, vB[i][0]);  fma4(aR, w0.y, vB[i][1]);
        fma4(aR, w0.z, vB[i][2]);  fma4(aR, w0.w, vB[i][3]);
        fma4(aZ, w1.x, vB[i][0]);  fma4(aZ, w1.y, vB[i][1]);
        fma4(aZ, w1.z, vB[i][2]);  fma4(aZ, w1.w, vB[i][3]);
        fma4(aNh, w2.x, vB[i][0]); fma4(aNh, w2.y, vB[i][1]);
        fma4(aNh, w2.z, vB[i][2]); fma4(aNh, w2.w, vB[i][3]);
      }
      // butterfly all-reduce over the 32-lane half (exact round-3 order)
#pragma unroll
      for (int m = 1; m <= 16; m <<= 1) {
#pragma unroll
        for (int c2 = 0; c2 < 4; ++c2) {
          aR[c2]  += __shfl_xor(aR[c2],  m);
          aZ[c2]  += __shfl_xor(aZ[c2],  m);
          aNi[c2] += __shfl_xor(aNi[c2], m);
          aNh[c2] += __shfl_xor(aNh[c2], m);
        }
      }
      // gate combine: lanes ks<4 handle batch b = q*4 + ks
      if (ks < 4) {
        const float bi0 = wlds[24960 + 0 * 8 + col];
        const float bi1 = wlds[24960 + 1 * 8 + col];
        const float bi2 = wlds[24960 + 2 * 8 + col];
        const float bh0 = wlds[24960 + 24 + 0 * 8 + col];
        const float bh1 = wlds[24960 + 24 + 1 * 8 + col];
        const float bh2 = wlds[24960 + 24 + 2 * 8 + col];
        const float sR  = pick4(aR, ks);
        const float sZ  = pick4(aZ, ks);
        const float sNi = pick4(aNi, ks);
        const float sNh = pick4(aNh, ks);
        const float r = 1.f / (1.f + expf(-(sR + bi0 + bh0)));
        const float z = 1.f / (1.f + expf(-(sZ + bi1 + bh1)));
        const float n = tanhf(sNi + bi2 + r * (sNh + bh2));
        const float ho = inB[jg * 4 + ks];   // plain: line already L1-hot
        const float hn = (1.f - z) * n + z * ho;
        astore_f(ringown + (size_t)((t + 1) & (kD - 1)) * kHSlot
                         + (q * kH + jg) * 4 + ks, hn);
        if (Lb == 2)
          P.out_h[((size_t)(q * 4 + ks) * kT + t) * kH + jg] = hn;
      }
    }

    // ---- publish: syncthreads drains sc-stores (vmcnt 0), then counter ----
    __syncthreads();
    if (tid == 0) astore_i(&progown[rank], t + 1);
  }
}

// ---------------------------------------------------------------------------
// Kernel 3: fused head (unchanged; bit-identical to rounds 1/3/6/7/8/10/11).
// ---------------------------------------------------------------------------
__global__ __launch_bounds__(256) void out_mask(
    const float* __restrict__ A,   // out_h [B*T][H]
    const float* __restrict__ w1, const float* __restrict__ bl1,
    const float* __restrict__ w2, const float* __restrict__ bl2,
    const float* __restrict__ x,   // [B*T][F]
    float* __restrict__ o1, float* __restrict__ o2) {
  __shared__ float As[16][68], W1s[16][68], W2s[16][68];
  const int tid = threadIdx.x;
  const int n0 = blockIdx.x * 64;
  const int m0 = blockIdx.y * 64;
  const int tn = tid & 15, tm = tid >> 4;
  const int lr = tid >> 2;
  const int lk = (tid & 3) * 4;

  float ac1[4][4], ac2[4][4];
#pragma unroll
  for (int mm = 0; mm < 4; ++mm)
#pragma unroll
    for (int nn = 0; nn < 4; ++nn) { ac1[mm][nn] = 0.f; ac2[mm][nn] = 0.f; }

  for (int k0 = 0; k0 < kH; k0 += 16) {
    const float4 av = *reinterpret_cast<const float4*>(A + (size_t)(m0 + lr) * kH + k0 + lk);
    const int fA = n0 + lr;
    float4 wv1 = make_float4(0.f, 0.f, 0.f, 0.f);
    float4 wv2 = make_float4(0.f, 0.f, 0.f, 0.f);
    if (fA < kF) {
      wv1 = *reinterpret_cast<const float4*>(w1 + (size_t)fA * kH + k0 + lk);
      wv2 = *reinterpret_cast<const float4*>(w2 + (size_t)fA * kH + k0 + lk);
    }
    __syncthreads();
    As[lk + 0][lr] = av.x;  As[lk + 1][lr] = av.y;  As[lk + 2][lr] = av.z;  As[lk + 3][lr] = av.w;
    W1s[lk + 0][lr] = wv1.x; W1s[lk + 1][lr] = wv1.y; W1s[lk + 2][lr] = wv1.z; W1s[lk + 3][lr] = wv1.w;
    W2s[lk + 0][lr] = wv2.x; W2s[lk + 1][lr] = wv2.y; W2s[lk + 2][lr] = wv2.z; W2s[lk + 3][lr] = wv2.w;
    __syncthreads();
#pragma unroll
    for (int kk = 0; kk < 16; ++kk) {
      const float4 a = *reinterpret_cast<const float4*>(&As[kk][tm * 4]);
      const float4 uu4 = *reinterpret_cast<const float4*>(&W1s[kk][tn * 4]);
      const float4 vv4 = *reinterpret_cast<const float4*>(&W2s[kk][tn * 4]);
      const float aa[4] = {a.x, a.y, a.z, a.w};
      const float uu[4] = {uu4.x, uu4.y, uu4.z, uu4.w};
      const float vv[4] = {vv4.x, vv4.y, vv4.z, vv4.w};
#pragma unroll
      for (int mm = 0; mm < 4; ++mm)
#pragma unroll
        for (int nn = 0; nn < 4; ++nn) {
          ac1[mm][nn] += aa[mm] * uu[nn];
          ac2[mm][nn] += aa[mm] * vv[nn];
        }
    }
  }
#pragma unroll
  for (int mm = 0; mm < 4; ++mm) {
    const int row = m0 + tm * 4 + mm;
#pragma unroll
    for (int nn = 0; nn < 4; ++nn) {
      const int f = n0 + tn * 4 + nn;
      if (f < kF) {
        const float s1 = fmaxf(ac1[mm][nn] + bl1[f], 0.f);
        const float s2 = fmaxf(ac2[mm][nn] + bl2[f], 0.f);
        const float inv = 1.f / (s1 + s2 + 1e-16f);
        const float xv = x[(size_t)row * kF + f];
        o1[(size_t)row * kF + f] = s1 * inv * xv;
        o2[(size_t)row * kF + f] = s2 * inv * xv;
      }
    }
  }
}

// ---------------------------------------------------------------------------
extern "C" void kernel_launch(void* const* d_in, const int* in_sizes, int n_in,
                              void* d_out, int out_size, void* d_ws, size_t ws_size,
                              hipStream_t stream) {
  const float* x = (const float*)d_in[0];
  GruParams P;
  P.wih[0] = (const float*)d_in[1];  P.whh[0] = (const float*)d_in[2];
  P.bih[0] = (const float*)d_in[3];  P.bhh[0] = (const float*)d_in[4];
  P.wih[1] = (const float*)d_in[5];  P.whh[1] = (const float*)d_in[6];
  P.bih[1] = (const float*)d_in[7];  P.bhh[1] = (const float*)d_in[8];
  P.wih[2] = (const float*)d_in[9];  P.whh[2] = (const float*)d_in[10];
  P.bih[2] = (const float*)d_in[11]; P.bhh[2] = (const float*)d_in[12];
  const float* w_l1 = (const float*)d_in[13];
  const float* b_l1 = (const float*)d_in[14];
  const float* w_l2 = (const float*)d_in[15];
  const float* b_l2 = (const float*)d_in[16];

  // ws layout (round-1-proven ~66 MB footprint): xq | out_h | prog | lall
  float* xq = (float*)d_ws;                              // 8,404,992 floats
  float* out_h = xq + (size_t)kT * 8 * kF * 4;           // 8,388,608 floats
  int* prog = (int*)(out_h + (size_t)kB * kT * kH);      // 192 ints (pad 256)
  int* lall = prog + 256;                                // 3 x stride-32 ints
  P.xq = xq;
  P.out_h = out_h;
  P.prog = prog;
  P.lall = lall;

  // rings live in d_out's o1 region (12 MB of 33.6 MB; dead before out_mask
  // overwrites o1). o1/o2 are the final outputs.
  float* o1 = (float*)d_out;
  float* o2 = o1 + (size_t)kB * kT * kF;
  const size_t ringSz = (size_t)kD * kHSlot;             // 4 MB each
  for (int l = 0; l < 3; ++l) P.ring[l] = o1 + (size_t)l * ringSz;

  // zero prog + lall and slot 0 (= h(0) = 0) of each ring (every call)
  hipMemsetAsync(prog, 0, 512 * sizeof(int), stream);
  hipMemsetAsync(P.ring[0], 0, kHSlot * sizeof(float), stream);
  hipMemsetAsync(P.ring[1], 0, kHSlot * sizeof(float), stream);
  hipMemsetAsync(P.ring[2], 0, kHSlot * sizeof(float), stream);

  transpose_x<<<dim3(17, kT), 256, 0, stream>>>(x, xq);

  void* args[] = { (void*)&P };
  hipLaunchCooperativeKernel((void*)gru_seq, dim3(195), dim3(256), args, 0u, stream);

  out_mask<<<dim3(9, 256), 256, 0, stream>>>(out_h, w_l1, b_l1, w_l2, b_l2, x, o1, o2);
}

// Round 13
// 8497.934 us; speedup vs baseline: 1.5202x; 1.2578x over previous
//
#include <hip/hip_runtime.h>
#include <cstddef>

// Problem dims
constexpr int kB = 32;    // batch
constexpr int kT = 512;   // time steps
constexpr int kF = 513;   // input features
constexpr int kH = 512;   // hidden
constexpr int kHSlot = kH * kB;   // floats per h slot (16384 = 64 KB)
constexpr int kD = 64;            // ring depth (power of 2)

// ---------------------------------------------------------------------------
// Agent-coherent helpers (relaxed atomics -> coherence point). sc-stores
// publish h/counters; sc-loads only for counters. Bulk h reads are plain
// cached loads guarded by the per-generation __threadfence (r11/r12-proven).
// ---------------------------------------------------------------------------
__device__ __forceinline__ void astore_f2(float* p, float a, float b) {
  const unsigned long long u =
      ((unsigned long long)__float_as_uint(b) << 32) | __float_as_uint(a);
  __hip_atomic_store(reinterpret_cast<unsigned long long*>(p), u,
                     __ATOMIC_RELAXED, __HIP_MEMORY_SCOPE_AGENT);
}
__device__ __forceinline__ int aload_i(const int* p) {
  return __hip_atomic_load(const_cast<int*>(p), __ATOMIC_RELAXED,
                           __HIP_MEMORY_SCOPE_AGENT);
}
__device__ __forceinline__ void astore_i(int* p, int v) {
  __hip_atomic_store(p, v, __ATOMIC_RELAXED, __HIP_MEMORY_SCOPE_AGENT);
}

// ---------------------------------------------------------------------------
// Kernel 1: transpose x [B][T][F] -> xq [T][8][F][4]  (quad-blocked batch)
// ---------------------------------------------------------------------------
__global__ __launch_bounds__(256) void transpose_x(const float* __restrict__ x,
                                                   float* __restrict__ xq) {
  __shared__ float s[32][33];
  const int f0 = blockIdx.x * 32;
  const int t  = blockIdx.y;
  const int i  = threadIdx.x;
  const int lo = i & 31;
  const int g8 = i >> 5;  // 0..7
#pragma unroll
  for (int qq = 0; qq < 4; ++qq) {
    const int b = g8 * 4 + qq;
    const int f = f0 + lo;
    float v = 0.f;
    if (f < kF) v = x[((size_t)b * kT + t) * kF + f];
    s[b][lo] = v;
  }
  __syncthreads();
  const int r  = lo & 3;
  const int fl = lo >> 2;  // 0..7
#pragma unroll
  for (int it = 0; it < 4; ++it) {
    const int f = f0 + fl + 8 * it;
    if (f < kF)
      xq[((size_t)(t * 8 + g8) * kF + f) * 4 + r] = s[g8 * 4 + r][fl + 8 * it];
  }
}

// ---------------------------------------------------------------------------
// Kernel 2: persistent GRU, layer-decoupled dataflow over depth-64 rings
// (r12 structure: 3 aggregator blocks + 192 compute blocks). Change vs r12:
// the 5-level x 16-value butterfly all-reduce (80 ds_swizzle/col; the LDS-
// pipe floor) is replaced by a REDUCE-SCATTER with the IDENTICAL binary
// reduction tree (bit-exact: same level-m lane-group pairings; IEEE addition
// is commutative, only the value count per level shrinks): rounds 1-2
// (xor 1,2) halve the c-dimension with lane-bit-aligned keep/send selects,
// rounds 3-5 (xor 4,8,16) run full-width on 4 values -> 24 swizzles/col.
// Lane ks ends with the reduced sums for c = ks&3, bit-identical to the old
// pick4(a, ks) at lanes ks<4. hn gathered to lane 0 (3 shfl) and published
// as two 8B sc-stores (same bytes, same addresses as the old 4 scalars).
// ---------------------------------------------------------------------------
struct GruParams {
  const float* xq;       // [T][8][513][4]
  const float* wih[3];   // [3H][KA]
  const float* whh[3];   // [3H][H]
  const float* bih[3];
  const float* bhh[3];
  float* ring[3];        // [kD][8][512][4] ring of h slots per layer
  float* out_h;          // [B*T][H]
  int* prog;             // [3][64] monotone per-block progress
  int* lall;             // [3] stride-32 line-isolated layer progress
};

__device__ __forceinline__ void fma4(float a[4], float w, float4 v) {
  a[0] = fmaf(w, v.x, a[0]);
  a[1] = fmaf(w, v.y, a[1]);
  a[2] = fmaf(w, v.z, a[2]);
  a[3] = fmaf(w, v.w, a[3]);
}

__global__ __launch_bounds__(256, 1) void gru_seq(GruParams P) {
  // weights: segA rows (g*8+c)*520, segB at +12480; biases at 24960 (48)
  __shared__ float wlds[25008];  // 100.0 KB

  const int tid = threadIdx.x;

  // ---- dedicated aggregator blocks: sweep raw counters, publish lall ----
  if (blockIdx.x >= 192) {
    const int L = blockIdx.x - 192;
    const int* cnt = P.prog + L * 64;
    if (tid < 64) {
      for (int t = 1; t <= kT; ++t) {
        for (;;) {
          const bool ok = (aload_i(&cnt[tid]) >= t);
          if (__ballot(ok) == ~0ull) break;
          __builtin_amdgcn_s_sleep(2);
        }
        if (tid == 0) astore_i(&P.lall[L * 32], t);
      }
    }
    return;
  }

  const int ks   = tid & 31;        // lane k-slice (round-3 semantics)
  const int q    = tid >> 5;        // unit = batch quad 0..7
  const int Lb   = blockIdx.x >> 6; // this block's layer 0..2
  const int rank = blockIdx.x & 63; // rank within layer-group
  const int jc0  = rank * 8;

  // ---- one-time weight + bias preload into LDS (this layer, 8 columns) ----
  {
    const float* wihL = P.wih[Lb];
    const float* whhL = P.whh[Lb];
    const int KA = (Lb == 0) ? kF : kH;
    for (int g = 0; g < 3; ++g)
      for (int c = 0; c < 8; ++c) {
        const int row = g * 8 + c;
        const float* sA = wihL + (size_t)(g * kH + jc0 + c) * KA;
        float* dA = &wlds[row * 520];
        for (int k = tid; k < KA; k += 256) dA[k] = sA[k];
        const float* sB = whhL + (size_t)(g * kH + jc0 + c) * kH;
        float* dB = &wlds[12480 + row * 520];
        for (int k = tid; k < kH; k += 256) dB[k] = sB[k];
      }
    if (tid < 48) {
      const int s2 = tid / 24;          // 0 = ih, 1 = hh
      const int g  = (tid % 24) / 8;
      const int c  = tid & 7;
      const float* src = s2 ? P.bhh[Lb] : P.bih[Lb];
      wlds[24960 + tid] = src[g * kH + jc0 + c];
    }
  }
  __syncthreads();

  float* ringown = P.ring[Lb];
  const float* ringup = (Lb > 0) ? P.ring[Lb - 1] : nullptr;
  int* progown = P.prog + Lb * 64;
  const int b0 = ks & 1;
  const int b1 = (ks >> 1) & 1;

  for (int t = 0; t < kT; ++t) {
    // ---- dataflow gate: 3 lanes poll 3 line-isolated lall words ----
    if (tid < 64) {
      for (;;) {
        bool ok = true;
        if (tid == 0) ok = (aload_i(&P.lall[Lb * 32]) >= t);
        else if (tid == 1 && Lb > 0) ok = (aload_i(&P.lall[(Lb - 1) * 32]) >= t + 1);
        else if (tid == 2 && Lb < 2) ok = (aload_i(&P.lall[(Lb + 1) * 32]) >= t - (kD - 1));
        if (__ballot(ok) == ~0ull) break;
        __builtin_amdgcn_s_sleep(2);
      }
    }
    // ---- generation-crossing acquire (r11-proven): invalidate L1/L2 so
    // plain loads refetch fresh ring lines; 16x per run per block.
    if (tid == 0) {
      const int tm = t & (kD - 1);
      if (tm == 0 || tm == kD - 1) __threadfence();
    }
    __syncthreads();

    const float* inB = ringown + (size_t)(t & (kD - 1)) * kHSlot + q * (kH * 4);

    // ---- load this lane's input quads ONCE (plain, cached; live 8 cols) ----
    float4 vA[4][4], vB[4][4];
    if (Lb == 0) {
      const float* inA = P.xq + ((size_t)t * 8 + q) * (kF * 4);
#pragma unroll
      for (int i = 0; i < 4; ++i) {
        const int k = 4 * ks + 128 * i;
#pragma unroll
        for (int m = 0; m < 4; ++m) {
          vA[i][m] = *reinterpret_cast<const float4*>(inA + (size_t)(k + m) * 4);
          vB[i][m] = *reinterpret_cast<const float4*>(inB + (size_t)(k + m) * 4);
        }
      }
    } else {
      const float* inA = ringup + (size_t)((t + 1) & (kD - 1)) * kHSlot + q * (kH * 4);
#pragma unroll
      for (int i = 0; i < 4; ++i) {
        const int k = 4 * ks + 128 * i;
#pragma unroll
        for (int m = 0; m < 4; ++m) {
          vA[i][m] = *reinterpret_cast<const float4*>(inA + (size_t)(k + m) * 4);
          vB[i][m] = *reinterpret_cast<const float4*>(inB + (size_t)(k + m) * 4);
        }
      }
    }
    float4 vE = make_float4(0.f, 0.f, 0.f, 0.f);
    if (Lb == 0 && ks == 0)
      vE = *reinterpret_cast<const float4*>(P.xq + ((size_t)t * 8 + q) * (kF * 4)
                                            + (size_t)512 * 4);

    // ---- 8 columns sequentially; per-lane accumulation bit-exact r3..r12 ----
#pragma unroll 1
    for (int col = 0; col < 8; ++col) {
      const int jg  = jc0 + col;       // global column
      const float* wa0 = &wlds[(0 * 8 + col) * 520];
      const float* wa1 = &wlds[(1 * 8 + col) * 520];
      const float* wa2 = &wlds[(2 * 8 + col) * 520];
      const float* wb0 = &wlds[12480 + (0 * 8 + col) * 520];
      const float* wb1 = &wlds[12480 + (1 * 8 + col) * 520];
      const float* wb2 = &wlds[12480 + (2 * 8 + col) * 520];

      float aR[4]  = {0.f, 0.f, 0.f, 0.f};
      float aZ[4]  = {0.f, 0.f, 0.f, 0.f};
      float aNi[4] = {0.f, 0.f, 0.f, 0.f};
      float aNh[4] = {0.f, 0.f, 0.f, 0.f};

      // segment A: w_ih . in
#pragma unroll
      for (int i = 0; i < 4; ++i) {
        const int k = 4 * ks + 128 * i;
        const float4 w0 = *reinterpret_cast<const float4*>(wa0 + k);
        const float4 w1 = *reinterpret_cast<const float4*>(wa1 + k);
        const float4 w2 = *reinterpret_cast<const float4*>(wa2 + k);
        fma4(aR, w0.x, vA[i][0]);  fma4(aR, w0.y, vA[i][1]);
        fma4(aR, w0.z, vA[i][2]);  fma4(aR, w0.w, vA[i][3]);
        fma4(aZ, w1.x, vA[i][0]);  fma4(aZ, w1.y, vA[i][1]);
        fma4(aZ, w1.z, vA[i][2]);  fma4(aZ, w1.w, vA[i][3]);
        fma4(aNi, w2.x, vA[i][0]); fma4(aNi, w2.y, vA[i][1]);
        fma4(aNi, w2.z, vA[i][2]); fma4(aNi, w2.w, vA[i][3]);
      }
      if (Lb == 0 && ks == 0) {  // edge column k = 512 (after segA)
        fma4(aR,  wa0[512], vE);
        fma4(aZ,  wa1[512], vE);
        fma4(aNi, wa2[512], vE);
      }
      // segment B: w_hh . h_old (R,Z chain into same accumulators)
#pragma unroll
      for (int i = 0; i < 4; ++i) {
        const int k = 4 * ks + 128 * i;
        const float4 w0 = *reinterpret_cast<const float4*>(wb0 + k);
        const float4 w1 = *reinterpret_cast<const float4*>(wb1 + k);
        const float4 w2 = *reinterpret_cast<const float4*>(wb2 + k);
        fma4(aR, w0.x, vB[i][0]);  fma4(aR, w0.y, vB[i][1]);
        fma4(aR, w0.z, vB[i][2]);  fma4(aR, w0.w, vB[i][3]);
        fma4(aZ, w1.x, vB[i][0]);  fma4(aZ, w1.y, vB[i][1]);
        fma4(aZ, w1.z, vB[i][2]);  fma4(aZ, w1.w, vB[i][3]);
        fma4(aNh, w2.x, vB[i][0]); fma4(aNh, w2.y, vB[i][1]);
        fma4(aNh, w2.z, vB[i][2]); fma4(aNh, w2.w, vB[i][3]);
      }

      // ---- reduce-scatter: same reduction tree as the r3 butterfly ----
      // Round 1 (xor 1): keep c with bit0(c)==bit0(ks); send the other.
      float kp, sd;
      kp = b0 ? aR[1] : aR[0];   sd = b0 ? aR[0] : aR[1];
      const float uR0 = kp + __shfl_xor(sd, 1);
      kp = b0 ? aR[3] : aR[2];   sd = b0 ? aR[2] : aR[3];
      const float uR1 = kp + __shfl_xor(sd, 1);
      kp = b0 ? aZ[1] : aZ[0];   sd = b0 ? aZ[0] : aZ[1];
      const float uZ0 = kp + __shfl_xor(sd, 1);
      kp = b0 ? aZ[3] : aZ[2];   sd = b0 ? aZ[2] : aZ[3];
      const float uZ1 = kp + __shfl_xor(sd, 1);
      kp = b0 ? aNi[1] : aNi[0]; sd = b0 ? aNi[0] : aNi[1];
      const float uNi0 = kp + __shfl_xor(sd, 1);
      kp = b0 ? aNi[3] : aNi[2]; sd = b0 ? aNi[2] : aNi[3];
      const float uNi1 = kp + __shfl_xor(sd, 1);
      kp = b0 ? aNh[1] : aNh[0]; sd = b0 ? aNh[0] : aNh[1];
      const float uNh0 = kp + __shfl_xor(sd, 1);
      kp = b0 ? aNh[3] : aNh[2]; sd = b0 ? aNh[2] : aNh[3];
      const float uNh1 = kp + __shfl_xor(sd, 1);
      // Round 2 (xor 2): keep c with bit1(c)==bit1(ks).
      kp = b1 ? uR1 : uR0;   sd = b1 ? uR0 : uR1;
      float wR = kp + __shfl_xor(sd, 2);
      kp = b1 ? uZ1 : uZ0;   sd = b1 ? uZ0 : uZ1;
      float wZ = kp + __shfl_xor(sd, 2);
      kp = b1 ? uNi1 : uNi0; sd = b1 ? uNi0 : uNi1;
      float wNi = kp + __shfl_xor(sd, 2);
      kp = b1 ? uNh1 : uNh0; sd = b1 ? uNh0 : uNh1;
      float wNh = kp + __shfl_xor(sd, 2);
      // Rounds 3-5 (xor 4, 8, 16): full-width on the 4 surviving values.
      wR  += __shfl_xor(wR, 4);  wZ  += __shfl_xor(wZ, 4);
      wNi += __shfl_xor(wNi, 4); wNh += __shfl_xor(wNh, 4);
      wR  += __shfl_xor(wR, 8);  wZ  += __shfl_xor(wZ, 8);
      wNi += __shfl_xor(wNi, 8); wNh += __shfl_xor(wNh, 8);
      wR  += __shfl_xor(wR, 16);  wZ  += __shfl_xor(wZ, 16);
      wNi += __shfl_xor(wNi, 16); wNh += __shfl_xor(wNh, 16);

      // gate combine: lane ks (<4) holds sums for c = ks (== ks&3)
      float hn = 0.f;
      if (ks < 4) {
        const float bi0 = wlds[24960 + 0 * 8 + col];
        const float bi1 = wlds[24960 + 1 * 8 + col];
        const float bi2 = wlds[24960 + 2 * 8 + col];
        const float bh0 = wlds[24960 + 24 + 0 * 8 + col];
        const float bh1 = wlds[24960 + 24 + 1 * 8 + col];
        const float bh2 = wlds[24960 + 24 + 2 * 8 + col];
        const float r = 1.f / (1.f + expf(-(wR + bi0 + bh0)));
        const float z = 1.f / (1.f + expf(-(wZ + bi1 + bh1)));
        const float n = tanhf(wNi + bi2 + r * (wNh + bh2));
        const float ho = inB[jg * 4 + ks];   // plain: line already L1-hot
        hn = (1.f - z) * n + z * ho;
        if (Lb == 2)
          P.out_h[((size_t)(q * 4 + ks) * kT + t) * kH + jg] = hn;
      }
      // gather lanes 0..3 -> lane 0, publish as two 8B sc-stores
      const float h1 = __shfl_xor(hn, 1);
      const float h2 = __shfl_xor(hn, 2);
      const float h3 = __shfl_xor(hn, 3);
      if (ks == 0) {
        float* dst = ringown + (size_t)((t + 1) & (kD - 1)) * kHSlot
                             + (q * kH + jg) * 4;
        astore_f2(dst, hn, h1);
        astore_f2(dst + 2, h2, h3);
      }
    }

    // ---- publish: syncthreads drains sc-stores (vmcnt 0), then counter ----
    __syncthreads();
    if (tid == 0) astore_i(&progown[rank], t + 1);
  }
}

// ---------------------------------------------------------------------------
// Kernel 3: fused head (unchanged; bit-identical to rounds 1/3/6/7/8/10-12).
// ---------------------------------------------------------------------------
__global__ __launch_bounds__(256) void out_mask(
    const float* __restrict__ A,   // out_h [B*T][H]
    const float* __restrict__ w1, const float* __restrict__ bl1,
    const float* __restrict__ w2, const float* __restrict__ bl2,
    const float* __restrict__ x,   // [B*T][F]
    float* __restrict__ o1, float* __restrict__ o2) {
  __shared__ float As[16][68], W1s[16][68], W2s[16][68];
  const int tid = threadIdx.x;
  const int n0 = blockIdx.x * 64;
  const int m0 = blockIdx.y * 64;
  const int tn = tid & 15, tm = tid >> 4;
  const int lr = tid >> 2;
  const int lk = (tid & 3) * 4;

  float ac1[4][4], ac2[4][4];
#pragma unroll
  for (int mm = 0; mm < 4; ++mm)
#pragma unroll
    for (int nn = 0; nn < 4; ++nn) { ac1[mm][nn] = 0.f; ac2[mm][nn] = 0.f; }

  for (int k0 = 0; k0 < kH; k0 += 16) {
    const float4 av = *reinterpret_cast<const float4*>(A + (size_t)(m0 + lr) * kH + k0 + lk);
    const int fA = n0 + lr;
    float4 wv1 = make_float4(0.f, 0.f, 0.f, 0.f);
    float4 wv2 = make_float4(0.f, 0.f, 0.f, 0.f);
    if (fA < kF) {
      wv1 = *reinterpret_cast<const float4*>(w1 + (size_t)fA * kH + k0 + lk);
      wv2 = *reinterpret_cast<const float4*>(w2 + (size_t)fA * kH + k0 + lk);
    }
    __syncthreads();
    As[lk + 0][lr] = av.x;  As[lk + 1][lr] = av.y;  As[lk + 2][lr] = av.z;  As[lk + 3][lr] = av.w;
    W1s[lk + 0][lr] = wv1.x; W1s[lk + 1][lr] = wv1.y; W1s[lk + 2][lr] = wv1.z; W1s[lk + 3][lr] = wv1.w;
    W2s[lk + 0][lr] = wv2.x; W2s[lk + 1][lr] = wv2.y; W2s[lk + 2][lr] = wv2.z; W2s[lk + 3][lr] = wv2.w;
    __syncthreads();
#pragma unroll
    for (int kk = 0; kk < 16; ++kk) {
      const float4 a = *reinterpret_cast<const float4*>(&As[kk][tm * 4]);
      const float4 uu4 = *reinterpret_cast<const float4*>(&W1s[kk][tn * 4]);
      const float4 vv4 = *reinterpret_cast<const float4*>(&W2s[kk][tn * 4]);
      const float aa[4] = {a.x, a.y, a.z, a.w};
      const float uu[4] = {uu4.x, uu4.y, uu4.z, uu4.w};
      const float vv[4] = {vv4.x, vv4.y, vv4.z, vv4.w};
#pragma unroll
      for (int mm = 0; mm < 4; ++mm)
#pragma unroll
        for (int nn = 0; nn < 4; ++nn) {
          ac1[mm][nn] += aa[mm] * uu[nn];
          ac2[mm][nn] += aa[mm] * vv[nn];
        }
    }
  }
#pragma unroll
  for (int mm = 0; mm < 4; ++mm) {
    const int row = m0 + tm * 4 + mm;
#pragma unroll
    for (int nn = 0; nn < 4; ++nn) {
      const int f = n0 + tn * 4 + nn;
      if (f < kF) {
        const float s1 = fmaxf(ac1[mm][nn] + bl1[f], 0.f);
        const float s2 = fmaxf(ac2[mm][nn] + bl2[f], 0.f);
        const float inv = 1.f / (s1 + s2 + 1e-16f);
        const float xv = x[(size_t)row * kF + f];
        o1[(size_t)row * kF + f] = s1 * inv * xv;
        o2[(size_t)row * kF + f] = s2 * inv * xv;
      }
    }
  }
}

// ---------------------------------------------------------------------------
extern "C" void kernel_launch(void* const* d_in, const int* in_sizes, int n_in,
                              void* d_out, int out_size, void* d_ws, size_t ws_size,
                              hipStream_t stream) {
  const float* x = (const float*)d_in[0];
  GruParams P;
  P.wih[0] = (const float*)d_in[1];  P.whh[0] = (const float*)d_in[2];
  P.bih[0] = (const float*)d_in[3];  P.bhh[0] = (const float*)d_in[4];
  P.wih[1] = (const float*)d_in[5];  P.whh[1] = (const float*)d_in[6];
  P.bih[1] = (const float*)d_in[7];  P.bhh[1] = (const float*)d_in[8];
  P.wih[2] = (const float*)d_in[9];  P.whh[2] = (const float*)d_in[10];
  P.bih[2] = (const float*)d_in[11]; P.bhh[2] = (const float*)d_in[12];
  const float* w_l1 = (const float*)d_in[13];
  const float* b_l1 = (const float*)d_in[14];
  const float* w_l2 = (const float*)d_in[15];
  const float* b_l2 = (const float*)d_in[16];

  // ws layout (round-1-proven ~66 MB footprint): xq | out_h | prog | lall
  float* xq = (float*)d_ws;                              // 8,404,992 floats
  float* out_h = xq + (size_t)kT * 8 * kF * 4;           // 8,388,608 floats
  int* prog = (int*)(out_h + (size_t)kB * kT * kH);      // 192 ints (pad 256)
  int* lall = prog + 256;                                // 3 x stride-32 ints
  P.xq = xq;
  P.out_h = out_h;
  P.prog = prog;
  P.lall = lall;

  // rings live in d_out's o1 region (12 MB of 33.6 MB; dead before out_mask
  // overwrites o1). o1/o2 are the final outputs.
  float* o1 = (float*)d_out;
  float* o2 = o1 + (size_t)kB * kT * kF;
  const size_t ringSz = (size_t)kD * kHSlot;             // 4 MB each
  for (int l = 0; l < 3; ++l) P.ring[l] = o1 + (size_t)l * ringSz;

  // zero prog + lall and slot 0 (= h(0) = 0) of each ring (every call)
  hipMemsetAsync(prog, 0, 512 * sizeof(int), stream);
  hipMemsetAsync(P.ring[0], 0, kHSlot * sizeof(float), stream);
  hipMemsetAsync(P.ring[1], 0, kHSlot * sizeof(float), stream);
  hipMemsetAsync(P.ring[2], 0, kHSlot * sizeof(float), stream);

  transpose_x<<<dim3(17, kT), 256, 0, stream>>>(x, xq);

  void* args[] = { (void*)&P };
  hipLaunchCooperativeKernel((void*)gru_seq, dim3(195), dim3(256), args, 0u, stream);

  out_mask<<<dim3(9, 256), 256, 0, stream>>>(out_h, w_l1, b_l1, w_l2, b_l2, x, o1, o2);
}

// Round 14
// 8108.237 us; speedup vs baseline: 1.5932x; 1.0481x over previous
//
#include <hip/hip_runtime.h>
#include <cstddef>

// Problem dims
constexpr int kB = 32;    // batch
constexpr int kT = 512;   // time steps
constexpr int kF = 513;   // input features
constexpr int kH = 512;   // hidden
constexpr int kHSlot = kH * kB;   // floats per h slot (16384 = 64 KB)
constexpr int kD = 64;            // ring depth (power of 2)

// ---------------------------------------------------------------------------
// Agent-coherent helpers (relaxed atomics -> coherence point). sc-stores
// publish h/counters; sc-loads only for counters. Bulk h reads are plain
// cached loads guarded by the per-generation __threadfence (r11-r13 proven).
// ---------------------------------------------------------------------------
__device__ __forceinline__ void astore_f2(float* p, float a, float b) {
  const unsigned long long u =
      ((unsigned long long)__float_as_uint(b) << 32) | __float_as_uint(a);
  __hip_atomic_store(reinterpret_cast<unsigned long long*>(p), u,
                     __ATOMIC_RELAXED, __HIP_MEMORY_SCOPE_AGENT);
}
__device__ __forceinline__ int aload_i(const int* p) {
  return __hip_atomic_load(const_cast<int*>(p), __ATOMIC_RELAXED,
                           __HIP_MEMORY_SCOPE_AGENT);
}
__device__ __forceinline__ void astore_i(int* p, int v) {
  __hip_atomic_store(p, v, __ATOMIC_RELAXED, __HIP_MEMORY_SCOPE_AGENT);
}

// ---------------------------------------------------------------------------
// Kernel 1: transpose x [B][T][F] -> xq [T][8][F][4]  (quad-blocked batch)
// ---------------------------------------------------------------------------
__global__ __launch_bounds__(256) void transpose_x(const float* __restrict__ x,
                                                   float* __restrict__ xq) {
  __shared__ float s[32][33];
  const int f0 = blockIdx.x * 32;
  const int t  = blockIdx.y;
  const int i  = threadIdx.x;
  const int lo = i & 31;
  const int g8 = i >> 5;  // 0..7
#pragma unroll
  for (int qq = 0; qq < 4; ++qq) {
    const int b = g8 * 4 + qq;
    const int f = f0 + lo;
    float v = 0.f;
    if (f < kF) v = x[((size_t)b * kT + t) * kF + f];
    s[b][lo] = v;
  }
  __syncthreads();
  const int r  = lo & 3;
  const int fl = lo >> 2;  // 0..7
#pragma unroll
  for (int it = 0; it < 4; ++it) {
    const int f = f0 + fl + 8 * it;
    if (f < kF)
      xq[((size_t)(t * 8 + g8) * kF + f) * 4 + r] = s[g8 * 4 + r][fl + 8 * it];
  }
}

// ---------------------------------------------------------------------------
// Kernel 2: persistent GRU, layer-decoupled dataflow over depth-64 rings
// (r12/r13 structure: 3 aggregator blocks + 192 compute blocks). Change vs
// r13 (occupancy only; math bit-exact): 512-thread blocks -> 8 waves =
// 2 waves/SIMD so one wave's FMA hides the other's ds_read latency (r13 at
// 1 wave/SIMD exposed the LDS round-trip in every dependency chain).
// To fit the 128-VGPR cap: vB stays register-resident (reused by all 4 cols
// + supplies ho); vA is STREAMED per column (identical values, L1-resident
// across the 4 cols). Unit map (r7-proven): 16 half-wave units =
// (quad q = unit&7) x (col-half ch = unit>>3), each unit does 4 columns.
// Reduce-scatter, gate math, paired sc-store publish: r13 verbatim.
// ---------------------------------------------------------------------------
struct GruParams {
  const float* xq;       // [T][8][513][4]
  const float* wih[3];   // [3H][KA]
  const float* whh[3];   // [3H][H]
  const float* bih[3];
  const float* bhh[3];
  float* ring[3];        // [kD][8][512][4] ring of h slots per layer
  float* out_h;          // [B*T][H]
  int* prog;             // [3][64] monotone per-block progress
  int* lall;             // [3] stride-32 line-isolated layer progress
};

__device__ __forceinline__ void fma4(float a[4], float w, float4 v) {
  a[0] = fmaf(w, v.x, a[0]);
  a[1] = fmaf(w, v.y, a[1]);
  a[2] = fmaf(w, v.z, a[2]);
  a[3] = fmaf(w, v.w, a[3]);
}

__global__ __launch_bounds__(512, 2) void gru_seq(GruParams P) {
  // weights: segA rows (g*8+c)*520, segB at +12480; biases at 24960 (48)
  __shared__ float wlds[25008];  // 100.0 KB

  const int tid = threadIdx.x;

  // ---- dedicated aggregator blocks: sweep raw counters, publish lall ----
  if (blockIdx.x >= 192) {
    const int L = blockIdx.x - 192;
    const int* cnt = P.prog + L * 64;
    if (tid < 64) {
      for (int t = 1; t <= kT; ++t) {
        for (;;) {
          const bool ok = (aload_i(&cnt[tid]) >= t);
          if (__ballot(ok) == ~0ull) break;
          __builtin_amdgcn_s_sleep(2);
        }
        if (tid == 0) astore_i(&P.lall[L * 32], t);
      }
    }
    return;
  }

  const int ks   = tid & 31;        // lane k-slice (round-3 semantics)
  const int unit = tid >> 5;        // 0..15 half-wave units
  const int q    = unit & 7;        // batch quad
  const int ch   = unit >> 3;       // column half: cols ch*4 .. ch*4+3
  const int Lb   = blockIdx.x >> 6; // this block's layer 0..2
  const int rank = blockIdx.x & 63; // rank within layer-group
  const int jc0  = rank * 8;

  // ---- one-time weight + bias preload into LDS (this layer, 8 columns) ----
  {
    const float* wihL = P.wih[Lb];
    const float* whhL = P.whh[Lb];
    const int KA = (Lb == 0) ? kF : kH;
    for (int g = 0; g < 3; ++g)
      for (int c = 0; c < 8; ++c) {
        const int row = g * 8 + c;
        const float* sA = wihL + (size_t)(g * kH + jc0 + c) * KA;
        float* dA = &wlds[row * 520];
        for (int k = tid; k < KA; k += 512) dA[k] = sA[k];
        const float* sB = whhL + (size_t)(g * kH + jc0 + c) * kH;
        float* dB = &wlds[12480 + row * 520];
        for (int k = tid; k < kH; k += 512) dB[k] = sB[k];
      }
    if (tid < 48) {
      const int s2 = tid / 24;          // 0 = ih, 1 = hh
      const int g  = (tid % 24) / 8;
      const int c  = tid & 7;
      const float* src = s2 ? P.bhh[Lb] : P.bih[Lb];
      wlds[24960 + tid] = src[g * kH + jc0 + c];
    }
  }
  __syncthreads();

  float* ringown = P.ring[Lb];
  const float* ringup = (Lb > 0) ? P.ring[Lb - 1] : nullptr;
  int* progown = P.prog + Lb * 64;
  const int b0 = ks & 1;
  const int b1 = (ks >> 1) & 1;

  for (int t = 0; t < kT; ++t) {
    // ---- dataflow gate: 3 lanes of wave 0 poll 3 line-isolated words ----
    if (tid < 64) {
      for (;;) {
        bool ok = true;
        if (tid == 0) ok = (aload_i(&P.lall[Lb * 32]) >= t);
        else if (tid == 1 && Lb > 0) ok = (aload_i(&P.lall[(Lb - 1) * 32]) >= t + 1);
        else if (tid == 2 && Lb < 2) ok = (aload_i(&P.lall[(Lb + 1) * 32]) >= t - (kD - 1));
        if (__ballot(ok) == ~0ull) break;
        __builtin_amdgcn_s_sleep(2);
      }
    }
    // ---- generation-crossing acquire (r11-proven): invalidate L1/L2 so
    // plain loads refetch fresh ring lines; 16x per run per block.
    if (tid == 0) {
      const int tm = t & (kD - 1);
      if (tm == 0 || tm == kD - 1) __threadfence();
    }
    __syncthreads();

    const float* inB = ringown + (size_t)(t & (kD - 1)) * kHSlot + q * (kH * 4);
    const float* inA = (Lb == 0)
        ? (P.xq + ((size_t)t * 8 + q) * (kF * 4))
        : (ringup + (size_t)((t + 1) & (kD - 1)) * kHSlot + q * (kH * 4));

    // ---- vB register-resident (reused by all 4 cols + ho); vA streamed ----
    float4 vB[4][4];
#pragma unroll
    for (int i = 0; i < 4; ++i) {
      const int k = 4 * ks + 128 * i;
#pragma unroll
      for (int m = 0; m < 4; ++m)
        vB[i][m] = *reinterpret_cast<const float4*>(inB + (size_t)(k + m) * 4);
    }
    float4 vE = make_float4(0.f, 0.f, 0.f, 0.f);
    if (Lb == 0 && ks == 0)
      vE = *reinterpret_cast<const float4*>(inA + (size_t)512 * 4);

    // ---- 4 columns sequentially; per-column math bit-exact r13 ----
#pragma unroll 1
    for (int cc = 0; cc < 4; ++cc) {
      const int col = ch * 4 + cc;     // local column 0..7
      const int jg  = jc0 + col;       // global column
      const float* wa0 = &wlds[(0 * 8 + col) * 520];
      const float* wa1 = &wlds[(1 * 8 + col) * 520];
      const float* wa2 = &wlds[(2 * 8 + col) * 520];
      const float* wb0 = &wlds[12480 + (0 * 8 + col) * 520];
      const float* wb1 = &wlds[12480 + (1 * 8 + col) * 520];
      const float* wb2 = &wlds[12480 + (2 * 8 + col) * 520];

      float aR[4]  = {0.f, 0.f, 0.f, 0.f};
      float aZ[4]  = {0.f, 0.f, 0.f, 0.f};
      float aNi[4] = {0.f, 0.f, 0.f, 0.f};
      float aNh[4] = {0.f, 0.f, 0.f, 0.f};

      // segment A: w_ih . in (vA streamed just-in-time; same values/order)
#pragma unroll
      for (int i = 0; i < 4; ++i) {
        const int k = 4 * ks + 128 * i;
        const float4 a0 = *reinterpret_cast<const float4*>(inA + (size_t)(k + 0) * 4);
        const float4 a1 = *reinterpret_cast<const float4*>(inA + (size_t)(k + 1) * 4);
        const float4 a2 = *reinterpret_cast<const float4*>(inA + (size_t)(k + 2) * 4);
        const float4 a3 = *reinterpret_cast<const float4*>(inA + (size_t)(k + 3) * 4);
        const float4 w0 = *reinterpret_cast<const float4*>(wa0 + k);
        const float4 w1 = *reinterpret_cast<const float4*>(wa1 + k);
        const float4 w2 = *reinterpret_cast<const float4*>(wa2 + k);
        fma4(aR, w0.x, a0);  fma4(aR, w0.y, a1);
        fma4(aR, w0.z, a2);  fma4(aR, w0.w, a3);
        fma4(aZ, w1.x, a0);  fma4(aZ, w1.y, a1);
        fma4(aZ, w1.z, a2);  fma4(aZ, w1.w, a3);
        fma4(aNi, w2.x, a0); fma4(aNi, w2.y, a1);
        fma4(aNi, w2.z, a2); fma4(aNi, w2.w, a3);
      }
      if (Lb == 0 && ks == 0) {  // edge column k = 512 (after segA)
        fma4(aR,  wa0[512], vE);
        fma4(aZ,  wa1[512], vE);
        fma4(aNi, wa2[512], vE);
      }
      // segment B: w_hh . h_old (R,Z chain into same accumulators)
#pragma unroll
      for (int i = 0; i < 4; ++i) {
        const int k = 4 * ks + 128 * i;
        const float4 w0 = *reinterpret_cast<const float4*>(wb0 + k);
        const float4 w1 = *reinterpret_cast<const float4*>(wb1 + k);
        const float4 w2 = *reinterpret_cast<const float4*>(wb2 + k);
        fma4(aR, w0.x, vB[i][0]);  fma4(aR, w0.y, vB[i][1]);
        fma4(aR, w0.z, vB[i][2]);  fma4(aR, w0.w, vB[i][3]);
        fma4(aZ, w1.x, vB[i][0]);  fma4(aZ, w1.y, vB[i][1]);
        fma4(aZ, w1.z, vB[i][2]);  fma4(aZ, w1.w, vB[i][3]);
        fma4(aNh, w2.x, vB[i][0]); fma4(aNh, w2.y, vB[i][1]);
        fma4(aNh, w2.z, vB[i][2]); fma4(aNh, w2.w, vB[i][3]);
      }

      // ---- reduce-scatter: identical tree to r13 (bit-exact) ----
      float kp, sd;
      kp = b0 ? aR[1] : aR[0];   sd = b0 ? aR[0] : aR[1];
      const float uR0 = kp + __shfl_xor(sd, 1);
      kp = b0 ? aR[3] : aR[2];   sd = b0 ? aR[2] : aR[3];
      const float uR1 = kp + __shfl_xor(sd, 1);
      kp = b0 ? aZ[1] : aZ[0];   sd = b0 ? aZ[0] : aZ[1];
      const float uZ0 = kp + __shfl_xor(sd, 1);
      kp = b0 ? aZ[3] : aZ[2];   sd = b0 ? aZ[2] : aZ[3];
      const float uZ1 = kp + __shfl_xor(sd, 1);
      kp = b0 ? aNi[1] : aNi[0]; sd = b0 ? aNi[0] : aNi[1];
      const float uNi0 = kp + __shfl_xor(sd, 1);
      kp = b0 ? aNi[3] : aNi[2]; sd = b0 ? aNi[2] : aNi[3];
      const float uNi1 = kp + __shfl_xor(sd, 1);
      kp = b0 ? aNh[1] : aNh[0]; sd = b0 ? aNh[0] : aNh[1];
      const float uNh0 = kp + __shfl_xor(sd, 1);
      kp = b0 ? aNh[3] : aNh[2]; sd = b0 ? aNh[2] : aNh[3];
      const float uNh1 = kp + __shfl_xor(sd, 1);
      kp = b1 ? uR1 : uR0;   sd = b1 ? uR0 : uR1;
      float wR = kp + __shfl_xor(sd, 2);
      kp = b1 ? uZ1 : uZ0;   sd = b1 ? uZ0 : uZ1;
      float wZ = kp + __shfl_xor(sd, 2);
      kp = b1 ? uNi1 : uNi0; sd = b1 ? uNi0 : uNi1;
      float wNi = kp + __shfl_xor(sd, 2);
      kp = b1 ? uNh1 : uNh0; sd = b1 ? uNh0 : uNh1;
      float wNh = kp + __shfl_xor(sd, 2);
      wR  += __shfl_xor(wR, 4);  wZ  += __shfl_xor(wZ, 4);
      wNi += __shfl_xor(wNi, 4); wNh += __shfl_xor(wNh, 4);
      wR  += __shfl_xor(wR, 8);  wZ  += __shfl_xor(wZ, 8);
      wNi += __shfl_xor(wNi, 8); wNh += __shfl_xor(wNh, 8);
      wR  += __shfl_xor(wR, 16);  wZ  += __shfl_xor(wZ, 16);
      wNi += __shfl_xor(wNi, 16); wNh += __shfl_xor(wNh, 16);

      // gate combine: lane ks (<4) holds sums for c = ks
      float hn = 0.f;
      if (ks < 4) {
        const float bi0 = wlds[24960 + 0 * 8 + col];
        const float bi1 = wlds[24960 + 1 * 8 + col];
        const float bi2 = wlds[24960 + 2 * 8 + col];
        const float bh0 = wlds[24960 + 24 + 0 * 8 + col];
        const float bh1 = wlds[24960 + 24 + 1 * 8 + col];
        const float bh2 = wlds[24960 + 24 + 2 * 8 + col];
        const float r = 1.f / (1.f + expf(-(wR + bi0 + bh0)));
        const float z = 1.f / (1.f + expf(-(wZ + bi1 + bh1)));
        const float n = tanhf(wNi + bi2 + r * (wNh + bh2));
        const float ho = inB[jg * 4 + ks];   // plain: line already hot
        hn = (1.f - z) * n + z * ho;
        if (Lb == 2)
          P.out_h[((size_t)(q * 4 + ks) * kT + t) * kH + jg] = hn;
      }
      // gather lanes 0..3 -> lane 0, publish as two 8B sc-stores
      const float h1 = __shfl_xor(hn, 1);
      const float h2 = __shfl_xor(hn, 2);
      const float h3 = __shfl_xor(hn, 3);
      if (ks == 0) {
        float* dst = ringown + (size_t)((t + 1) & (kD - 1)) * kHSlot
                             + (q * kH + jg) * 4;
        astore_f2(dst, hn, h1);
        astore_f2(dst + 2, h2, h3);
      }
    }

    // ---- publish: syncthreads drains sc-stores (vmcnt 0), then counter ----
    __syncthreads();
    if (tid == 0) astore_i(&progown[rank], t + 1);
  }
}

// ---------------------------------------------------------------------------
// Kernel 3: fused head (unchanged; bit-identical to rounds 1/3/6-13).
// ---------------------------------------------------------------------------
__global__ __launch_bounds__(256) void out_mask(
    const float* __restrict__ A,   // out_h [B*T][H]
    const float* __restrict__ w1, const float* __restrict__ bl1,
    const float* __restrict__ w2, const float* __restrict__ bl2,
    const float* __restrict__ x,   // [B*T][F]
    float* __restrict__ o1, float* __restrict__ o2) {
  __shared__ float As[16][68], W1s[16][68], W2s[16][68];
  const int tid = threadIdx.x;
  const int n0 = blockIdx.x * 64;
  const int m0 = blockIdx.y * 64;
  const int tn = tid & 15, tm = tid >> 4;
  const int lr = tid >> 2;
  const int lk = (tid & 3) * 4;

  float ac1[4][4], ac2[4][4];
#pragma unroll
  for (int mm = 0; mm < 4; ++mm)
#pragma unroll
    for (int nn = 0; nn < 4; ++nn) { ac1[mm][nn] = 0.f; ac2[mm][nn] = 0.f; }

  for (int k0 = 0; k0 < kH; k0 += 16) {
    const float4 av = *reinterpret_cast<const float4*>(A + (size_t)(m0 + lr) * kH + k0 + lk);
    const int fA = n0 + lr;
    float4 wv1 = make_float4(0.f, 0.f, 0.f, 0.f);
    float4 wv2 = make_float4(0.f, 0.f, 0.f, 0.f);
    if (fA < kF) {
      wv1 = *reinterpret_cast<const float4*>(w1 + (size_t)fA * kH + k0 + lk);
      wv2 = *reinterpret_cast<const float4*>(w2 + (size_t)fA * kH + k0 + lk);
    }
    __syncthreads();
    As[lk + 0][lr] = av.x;  As[lk + 1][lr] = av.y;  As[lk + 2][lr] = av.z;  As[lk + 3][lr] = av.w;
    W1s[lk + 0][lr] = wv1.x; W1s[lk + 1][lr] = wv1.y; W1s[lk + 2][lr] = wv1.z; W1s[lk + 3][lr] = wv1.w;
    W2s[lk + 0][lr] = wv2.x; W2s[lk + 1][lr] = wv2.y; W2s[lk + 2][lr] = wv2.z; W2s[lk + 3][lr] = wv2.w;
    __syncthreads();
#pragma unroll
    for (int kk = 0; kk < 16; ++kk) {
      const float4 a = *reinterpret_cast<const float4*>(&As[kk][tm * 4]);
      const float4 uu4 = *reinterpret_cast<const float4*>(&W1s[kk][tn * 4]);
      const float4 vv4 = *reinterpret_cast<const float4*>(&W2s[kk][tn * 4]);
      const float aa[4] = {a.x, a.y, a.z, a.w};
      const float uu[4] = {uu4.x, uu4.y, uu4.z, uu4.w};
      const float vv[4] = {vv4.x, vv4.y, vv4.z, vv4.w};
#pragma unroll
      for (int mm = 0; mm < 4; ++mm)
#pragma unroll
        for (int nn = 0; nn < 4; ++nn) {
          ac1[mm][nn] += aa[mm] * uu[nn];
          ac2[mm][nn] += aa[mm] * vv[nn];
        }
    }
  }
#pragma unroll
  for (int mm = 0; mm < 4; ++mm) {
    const int row = m0 + tm * 4 + mm;
#pragma unroll
    for (int nn = 0; nn < 4; ++nn) {
      const int f = n0 + tn * 4 + nn;
      if (f < kF) {
        const float s1 = fmaxf(ac1[mm][nn] + bl1[f], 0.f);
        const float s2 = fmaxf(ac2[mm][nn] + bl2[f], 0.f);
        const float inv = 1.f / (s1 + s2 + 1e-16f);
        const float xv = x[(size_t)row * kF + f];
        o1[(size_t)row * kF + f] = s1 * inv * xv;
        o2[(size_t)row * kF + f] = s2 * inv * xv;
      }
    }
  }
}

// ---------------------------------------------------------------------------
extern "C" void kernel_launch(void* const* d_in, const int* in_sizes, int n_in,
                              void* d_out, int out_size, void* d_ws, size_t ws_size,
                              hipStream_t stream) {
  const float* x = (const float*)d_in[0];
  GruParams P;
  P.wih[0] = (const float*)d_in[1];  P.whh[0] = (const float*)d_in[2];
  P.bih[0] = (const float*)d_in[3];  P.bhh[0] = (const float*)d_in[4];
  P.wih[1] = (const float*)d_in[5];  P.whh[1] = (const float*)d_in[6];
  P.bih[1] = (const float*)d_in[7];  P.bhh[1] = (const float*)d_in[8];
  P.wih[2] = (const float*)d_in[9];  P.whh[2] = (const float*)d_in[10];
  P.bih[2] = (const float*)d_in[11]; P.bhh[2] = (const float*)d_in[12];
  const float* w_l1 = (const float*)d_in[13];
  const float* b_l1 = (const float*)d_in[14];
  const float* w_l2 = (const float*)d_in[15];
  const float* b_l2 = (const float*)d_in[16];

  // ws layout (round-1-proven ~66 MB footprint): xq | out_h | prog | lall
  float* xq = (float*)d_ws;                              // 8,404,992 floats
  float* out_h = xq + (size_t)kT * 8 * kF * 4;           // 8,388,608 floats
  int* prog = (int*)(out_h + (size_t)kB * kT * kH);      // 192 ints (pad 256)
  int* lall = prog + 256;                                // 3 x stride-32 ints
  P.xq = xq;
  P.out_h = out_h;
  P.prog = prog;
  P.lall = lall;

  // rings live in d_out's o1 region (12 MB of 33.6 MB; dead before out_mask
  // overwrites o1). o1/o2 are the final outputs.
  float* o1 = (float*)d_out;
  float* o2 = o1 + (size_t)kB * kT * kF;
  const size_t ringSz = (size_t)kD * kHSlot;             // 4 MB each
  for (int l = 0; l < 3; ++l) P.ring[l] = o1 + (size_t)l * ringSz;

  // zero prog + lall and slot 0 (= h(0) = 0) of each ring (every call)
  hipMemsetAsync(prog, 0, 512 * sizeof(int), stream);
  hipMemsetAsync(P.ring[0], 0, kHSlot * sizeof(float), stream);
  hipMemsetAsync(P.ring[1], 0, kHSlot * sizeof(float), stream);
  hipMemsetAsync(P.ring[2], 0, kHSlot * sizeof(float), stream);

  transpose_x<<<dim3(17, kT), 256, 0, stream>>>(x, xq);

  void* args[] = { (void*)&P };
  hipLaunchCooperativeKernel((void*)gru_seq, dim3(195), dim3(512), args, 0u, stream);

  out_mask<<<dim3(9, 256), 256, 0, stream>>>(out_h, w_l1, b_l1, w_l2, b_l2, x, o1, o2);
}

// Round 15
// 5397.066 us; speedup vs baseline: 2.3936x; 1.5023x over previous
//
#include <hip/hip_runtime.h>
#include <cstddef>

// Problem dims
constexpr int kB = 32;    // batch
constexpr int kT = 512;   // time steps
constexpr int kF = 513;   // input features
constexpr int kH = 512;   // hidden
constexpr int kHSlot = kH * kB;   // floats per h slot (16384 = 64 KB)
constexpr int kD = 64;            // ring depth (power of 2)

// ---------------------------------------------------------------------------
// Agent-coherent helpers (relaxed atomics -> coherence point). sc-stores
// publish h/counters; sc-loads only for counters. Bulk h reads are plain
// cached loads guarded by the per-generation __threadfence (r11-r14 proven).
// ---------------------------------------------------------------------------
__device__ __forceinline__ void astore_f2(float* p, float a, float b) {
  const unsigned long long u =
      ((unsigned long long)__float_as_uint(b) << 32) | __float_as_uint(a);
  __hip_atomic_store(reinterpret_cast<unsigned long long*>(p), u,
                     __ATOMIC_RELAXED, __HIP_MEMORY_SCOPE_AGENT);
}
__device__ __forceinline__ int aload_i(const int* p) {
  return __hip_atomic_load(const_cast<int*>(p), __ATOMIC_RELAXED,
                           __HIP_MEMORY_SCOPE_AGENT);
}
__device__ __forceinline__ void astore_i(int* p, int v) {
  __hip_atomic_store(p, v, __ATOMIC_RELAXED, __HIP_MEMORY_SCOPE_AGENT);
}

// ---------------------------------------------------------------------------
// Kernel 1: transpose x [B][T][F] -> xq [T][8][F][4]  (quad-blocked batch)
// ---------------------------------------------------------------------------
__global__ __launch_bounds__(256) void transpose_x(const float* __restrict__ x,
                                                   float* __restrict__ xq) {
  __shared__ float s[32][33];
  const int f0 = blockIdx.x * 32;
  const int t  = blockIdx.y;
  const int i  = threadIdx.x;
  const int lo = i & 31;
  const int g8 = i >> 5;  // 0..7
#pragma unroll
  for (int qq = 0; qq < 4; ++qq) {
    const int b = g8 * 4 + qq;
    const int f = f0 + lo;
    float v = 0.f;
    if (f < kF) v = x[((size_t)b * kT + t) * kF + f];
    s[b][lo] = v;
  }
  __syncthreads();
  const int r  = lo & 3;
  const int fl = lo >> 2;  // 0..7
#pragma unroll
  for (int it = 0; it < 4; ++it) {
    const int f = f0 + fl + 8 * it;
    if (f < kF)
      xq[((size_t)(t * 8 + g8) * kF + f) * 4 + r] = s[g8 * 4 + r][fl + 8 * it];
  }
}

// ---------------------------------------------------------------------------
// Kernel 2: persistent GRU, layer-decoupled dataflow over depth-64 rings
// (r12-r14 structure: 3 aggregator blocks + 192 compute blocks). Change vs
// r14 (phase pipelining only; per-column math bit-exact r13/r14):
//   * step split into two gated phases. Phase A (segA over inA) needs only
//     the UPSTREAM gate (L0: no gate at all); the SIBLING gate + inB
//     coherence-miss train then hide under segA's FMA work. Down-gate
//     (slot-write WAR) moves to the sibling gate (write happens after).
//   * launch_bounds(512,1): 8 waves/CU co-resident at <=256 VGPR (m69),
//     giving room for vA regs (segA phase) + 4-column accumulators + vB
//     regs (segB phase) without spill; phases keep peak ~180 VGPR.
//   * generation fences keep r11 placement relative to each ring read:
//     tm==63 before vA (upstream slot wrap), tm==0 before vB (own wrap).
// ---------------------------------------------------------------------------
struct GruParams {
  const float* xq;       // [T][8][513][4]
  const float* wih[3];   // [3H][KA]
  const float* whh[3];   // [3H][H]
  const float* bih[3];
  const float* bhh[3];
  float* ring[3];        // [kD][8][512][4] ring of h slots per layer
  float* out_h;          // [B*T][H]
  int* prog;             // [3][64] monotone per-block progress
  int* lall;             // [3] stride-32 line-isolated layer progress
};

__device__ __forceinline__ void fma4(float a[4], float w, float4 v) {
  a[0] = fmaf(w, v.x, a[0]);
  a[1] = fmaf(w, v.y, a[1]);
  a[2] = fmaf(w, v.z, a[2]);
  a[3] = fmaf(w, v.w, a[3]);
}

__global__ __launch_bounds__(512, 1) void gru_seq(GruParams P) {
  // weights: segA rows (g*8+c)*520, segB at +12480; biases at 24960 (48)
  __shared__ float wlds[25008];  // 100.0 KB

  const int tid = threadIdx.x;

  // ---- dedicated aggregator blocks: sweep raw counters, publish lall ----
  if (blockIdx.x >= 192) {
    const int L = blockIdx.x - 192;
    const int* cnt = P.prog + L * 64;
    if (tid < 64) {
      for (int t = 1; t <= kT; ++t) {
        for (;;) {
          const bool ok = (aload_i(&cnt[tid]) >= t);
          if (__ballot(ok) == ~0ull) break;
          __builtin_amdgcn_s_sleep(2);
        }
        if (tid == 0) astore_i(&P.lall[L * 32], t);
      }
    }
    return;
  }

  const int ks   = tid & 31;        // lane k-slice (round-3 semantics)
  const int unit = tid >> 5;        // 0..15 half-wave units
  const int q    = unit & 7;        // batch quad
  const int ch   = unit >> 3;       // column half: cols ch*4 .. ch*4+3
  const int Lb   = blockIdx.x >> 6; // this block's layer 0..2
  const int rank = blockIdx.x & 63; // rank within layer-group
  const int jc0  = rank * 8;

  // ---- one-time weight + bias preload into LDS (this layer, 8 columns) ----
  {
    const float* wihL = P.wih[Lb];
    const float* whhL = P.whh[Lb];
    const int KA = (Lb == 0) ? kF : kH;
    for (int g = 0; g < 3; ++g)
      for (int c = 0; c < 8; ++c) {
        const int row = g * 8 + c;
        const float* sA = wihL + (size_t)(g * kH + jc0 + c) * KA;
        float* dA = &wlds[row * 520];
        for (int k = tid; k < KA; k += 512) dA[k] = sA[k];
        const float* sB = whhL + (size_t)(g * kH + jc0 + c) * kH;
        float* dB = &wlds[12480 + row * 520];
        for (int k = tid; k < kH; k += 512) dB[k] = sB[k];
      }
    if (tid < 48) {
      const int s2 = tid / 24;          // 0 = ih, 1 = hh
      const int g  = (tid % 24) / 8;
      const int c  = tid & 7;
      const float* src = s2 ? P.bhh[Lb] : P.bih[Lb];
      wlds[24960 + tid] = src[g * kH + jc0 + c];
    }
  }
  __syncthreads();

  float* ringown = P.ring[Lb];
  const float* ringup = (Lb > 0) ? P.ring[Lb - 1] : nullptr;
  int* progown = P.prog + Lb * 64;
  const int b0 = ks & 1;
  const int b1 = (ks >> 1) & 1;

  for (int t = 0; t < kT; ++t) {
    const int tm = t & (kD - 1);

    // ======== PHASE A: upstream gate -> segA over inA ========
    if (Lb > 0) {
      if (tid < 64) {
        for (;;) {
          bool ok = true;
          if (tid == 0) ok = (aload_i(&P.lall[(Lb - 1) * 32]) >= t + 1);
          if (__ballot(ok) == ~0ull) break;
          __builtin_amdgcn_s_sleep(2);
        }
      }
      if (tid == 0 && tm == kD - 1) __threadfence();  // inA slot wrap
      __syncthreads();
    }

    const float* inA = (Lb == 0)
        ? (P.xq + ((size_t)t * 8 + q) * (kF * 4))
        : (ringup + (size_t)((t + 1) & (kD - 1)) * kHSlot + q * (kH * 4));

    // vA register-resident (reused by all 4 cols; values identical to r14)
    float4 vA[4][4];
#pragma unroll
    for (int i = 0; i < 4; ++i) {
      const int k = 4 * ks + 128 * i;
#pragma unroll
      for (int m = 0; m < 4; ++m)
        vA[i][m] = *reinterpret_cast<const float4*>(inA + (size_t)(k + m) * 4);
    }
    float4 vE = make_float4(0.f, 0.f, 0.f, 0.f);
    if (Lb == 0 && ks == 0)
      vE = *reinterpret_cast<const float4*>(inA + (size_t)512 * 4);

    // 4-column accumulators (first index static via full unroll)
    float accR[4][4], accZ[4][4], accNi[4][4], accNh[4][4];

    // segA for all 4 columns (per-column chain verbatim r13/r14)
#pragma unroll
    for (int cc = 0; cc < 4; ++cc) {
      const int col = ch * 4 + cc;
      const float* wa0 = &wlds[(0 * 8 + col) * 520];
      const float* wa1 = &wlds[(1 * 8 + col) * 520];
      const float* wa2 = &wlds[(2 * 8 + col) * 520];
#pragma unroll
      for (int c2 = 0; c2 < 4; ++c2) {
        accR[cc][c2] = 0.f; accZ[cc][c2] = 0.f;
        accNi[cc][c2] = 0.f; accNh[cc][c2] = 0.f;
      }
#pragma unroll
      for (int i = 0; i < 4; ++i) {
        const int k = 4 * ks + 128 * i;
        const float4 w0 = *reinterpret_cast<const float4*>(wa0 + k);
        const float4 w1 = *reinterpret_cast<const float4*>(wa1 + k);
        const float4 w2 = *reinterpret_cast<const float4*>(wa2 + k);
        fma4(accR[cc], w0.x, vA[i][0]);  fma4(accR[cc], w0.y, vA[i][1]);
        fma4(accR[cc], w0.z, vA[i][2]);  fma4(accR[cc], w0.w, vA[i][3]);
        fma4(accZ[cc], w1.x, vA[i][0]);  fma4(accZ[cc], w1.y, vA[i][1]);
        fma4(accZ[cc], w1.z, vA[i][2]);  fma4(accZ[cc], w1.w, vA[i][3]);
        fma4(accNi[cc], w2.x, vA[i][0]); fma4(accNi[cc], w2.y, vA[i][1]);
        fma4(accNi[cc], w2.z, vA[i][2]); fma4(accNi[cc], w2.w, vA[i][3]);
      }
      if (Lb == 0 && ks == 0) {  // edge column k = 512 (after segA)
        fma4(accR[cc],  wa0[512], vE);
        fma4(accZ[cc],  wa1[512], vE);
        fma4(accNi[cc], wa2[512], vE);
      }
    }

    // ======== PHASE B: sibling + down gate -> segB, reduce, publish ========
    if (tid < 64) {
      for (;;) {
        bool ok = true;
        if (tid == 0) ok = (aload_i(&P.lall[Lb * 32]) >= t);
        else if (tid == 1 && Lb < 2) ok = (aload_i(&P.lall[(Lb + 1) * 32]) >= t - (kD - 1));
        if (__ballot(ok) == ~0ull) break;
        __builtin_amdgcn_s_sleep(2);
      }
    }
    if (tid == 0 && tm == 0) __threadfence();  // inB slot wrap
    __syncthreads();

    const float* inB = ringown + (size_t)tm * kHSlot + q * (kH * 4);

    // vB register-resident (reused by all 4 cols + ho)
    float4 vB[4][4];
#pragma unroll
    for (int i = 0; i < 4; ++i) {
      const int k = 4 * ks + 128 * i;
#pragma unroll
      for (int m = 0; m < 4; ++m)
        vB[i][m] = *reinterpret_cast<const float4*>(inB + (size_t)(k + m) * 4);
    }

#pragma unroll
    for (int cc = 0; cc < 4; ++cc) {
      const int col = ch * 4 + cc;
      const int jg  = jc0 + col;
      const float* wb0 = &wlds[12480 + (0 * 8 + col) * 520];
      const float* wb1 = &wlds[12480 + (1 * 8 + col) * 520];
      const float* wb2 = &wlds[12480 + (2 * 8 + col) * 520];

      // segB: w_hh . h_old (R,Z chain into same accumulators; order = r13)
#pragma unroll
      for (int i = 0; i < 4; ++i) {
        const int k = 4 * ks + 128 * i;
        const float4 w0 = *reinterpret_cast<const float4*>(wb0 + k);
        const float4 w1 = *reinterpret_cast<const float4*>(wb1 + k);
        const float4 w2 = *reinterpret_cast<const float4*>(wb2 + k);
        fma4(accR[cc], w0.x, vB[i][0]);  fma4(accR[cc], w0.y, vB[i][1]);
        fma4(accR[cc], w0.z, vB[i][2]);  fma4(accR[cc], w0.w, vB[i][3]);
        fma4(accZ[cc], w1.x, vB[i][0]);  fma4(accZ[cc], w1.y, vB[i][1]);
        fma4(accZ[cc], w1.z, vB[i][2]);  fma4(accZ[cc], w1.w, vB[i][3]);
        fma4(accNh[cc], w2.x, vB[i][0]); fma4(accNh[cc], w2.y, vB[i][1]);
        fma4(accNh[cc], w2.z, vB[i][2]); fma4(accNh[cc], w2.w, vB[i][3]);
      }

      // reduce-scatter: identical tree to r13/r14 (bit-exact)
      float kp, sd;
      kp = b0 ? accR[cc][1] : accR[cc][0];   sd = b0 ? accR[cc][0] : accR[cc][1];
      const float uR0 = kp + __shfl_xor(sd, 1);
      kp = b0 ? accR[cc][3] : accR[cc][2];   sd = b0 ? accR[cc][2] : accR[cc][3];
      const float uR1 = kp + __shfl_xor(sd, 1);
      kp = b0 ? accZ[cc][1] : accZ[cc][0];   sd = b0 ? accZ[cc][0] : accZ[cc][1];
      const float uZ0 = kp + __shfl_xor(sd, 1);
      kp = b0 ? accZ[cc][3] : accZ[cc][2];   sd = b0 ? accZ[cc][2] : accZ[cc][3];
      const float uZ1 = kp + __shfl_xor(sd, 1);
      kp = b0 ? accNi[cc][1] : accNi[cc][0]; sd = b0 ? accNi[cc][0] : accNi[cc][1];
      const float uNi0 = kp + __shfl_xor(sd, 1);
      kp = b0 ? accNi[cc][3] : accNi[cc][2]; sd = b0 ? accNi[cc][2] : accNi[cc][3];
      const float uNi1 = kp + __shfl_xor(sd, 1);
      kp = b0 ? accNh[cc][1] : accNh[cc][0]; sd = b0 ? accNh[cc][0] : accNh[cc][1];
      const float uNh0 = kp + __shfl_xor(sd, 1);
      kp = b0 ? accNh[cc][3] : accNh[cc][2]; sd = b0 ? accNh[cc][2] : accNh[cc][3];
      const float uNh1 = kp + __shfl_xor(sd, 1);
      kp = b1 ? uR1 : uR0;   sd = b1 ? uR0 : uR1;
      float wR = kp + __shfl_xor(sd, 2);
      kp = b1 ? uZ1 : uZ0;   sd = b1 ? uZ0 : uZ1;
      float wZ = kp + __shfl_xor(sd, 2);
      kp = b1 ? uNi1 : uNi0; sd = b1 ? uNi0 : uNi1;
      float wNi = kp + __shfl_xor(sd, 2);
      kp = b1 ? uNh1 : uNh0; sd = b1 ? uNh0 : uNh1;
      float wNh = kp + __shfl_xor(sd, 2);
      wR  += __shfl_xor(wR, 4);  wZ  += __shfl_xor(wZ, 4);
      wNi += __shfl_xor(wNi, 4); wNh += __shfl_xor(wNh, 4);
      wR  += __shfl_xor(wR, 8);  wZ  += __shfl_xor(wZ, 8);
      wNi += __shfl_xor(wNi, 8); wNh += __shfl_xor(wNh, 8);
      wR  += __shfl_xor(wR, 16);  wZ  += __shfl_xor(wZ, 16);
      wNi += __shfl_xor(wNi, 16); wNh += __shfl_xor(wNh, 16);

      // gate combine: lane ks (<4) holds sums for c = ks
      float hn = 0.f;
      if (ks < 4) {
        const float bi0 = wlds[24960 + 0 * 8 + col];
        const float bi1 = wlds[24960 + 1 * 8 + col];
        const float bi2 = wlds[24960 + 2 * 8 + col];
        const float bh0 = wlds[24960 + 24 + 0 * 8 + col];
        const float bh1 = wlds[24960 + 24 + 1 * 8 + col];
        const float bh2 = wlds[24960 + 24 + 2 * 8 + col];
        const float r = 1.f / (1.f + expf(-(wR + bi0 + bh0)));
        const float z = 1.f / (1.f + expf(-(wZ + bi1 + bh1)));
        const float n = tanhf(wNi + bi2 + r * (wNh + bh2));
        const float ho = inB[jg * 4 + ks];   // plain: line already hot
        hn = (1.f - z) * n + z * ho;
        if (Lb == 2)
          P.out_h[((size_t)(q * 4 + ks) * kT + t) * kH + jg] = hn;
      }
      // gather lanes 0..3 -> lane 0, publish as two 8B sc-stores
      const float h1 = __shfl_xor(hn, 1);
      const float h2 = __shfl_xor(hn, 2);
      const float h3 = __shfl_xor(hn, 3);
      if (ks == 0) {
        float* dst = ringown + (size_t)((t + 1) & (kD - 1)) * kHSlot
                             + (q * kH + jg) * 4;
        astore_f2(dst, hn, h1);
        astore_f2(dst + 2, h2, h3);
      }
    }

    // ---- publish: syncthreads drains sc-stores (vmcnt 0), then counter ----
    __syncthreads();
    if (tid == 0) astore_i(&progown[rank], t + 1);
  }
}

// ---------------------------------------------------------------------------
// Kernel 3: fused head (unchanged; bit-identical to rounds 1/3/6-14).
// ---------------------------------------------------------------------------
__global__ __launch_bounds__(256) void out_mask(
    const float* __restrict__ A,   // out_h [B*T][H]
    const float* __restrict__ w1, const float* __restrict__ bl1,
    const float* __restrict__ w2, const float* __restrict__ bl2,
    const float* __restrict__ x,   // [B*T][F]
    float* __restrict__ o1, float* __restrict__ o2) {
  __shared__ float As[16][68], W1s[16][68], W2s[16][68];
  const int tid = threadIdx.x;
  const int n0 = blockIdx.x * 64;
  const int m0 = blockIdx.y * 64;
  const int tn = tid & 15, tm = tid >> 4;
  const int lr = tid >> 2;
  const int lk = (tid & 3) * 4;

  float ac1[4][4], ac2[4][4];
#pragma unroll
  for (int mm = 0; mm < 4; ++mm)
#pragma unroll
    for (int nn = 0; nn < 4; ++nn) { ac1[mm][nn] = 0.f; ac2[mm][nn] = 0.f; }

  for (int k0 = 0; k0 < kH; k0 += 16) {
    const float4 av = *reinterpret_cast<const float4*>(A + (size_t)(m0 + lr) * kH + k0 + lk);
    const int fA = n0 + lr;
    float4 wv1 = make_float4(0.f, 0.f, 0.f, 0.f);
    float4 wv2 = make_float4(0.f, 0.f, 0.f, 0.f);
    if (fA < kF) {
      wv1 = *reinterpret_cast<const float4*>(w1 + (size_t)fA * kH + k0 + lk);
      wv2 = *reinterpret_cast<const float4*>(w2 + (size_t)fA * kH + k0 + lk);
    }
    __syncthreads();
    As[lk + 0][lr] = av.x;  As[lk + 1][lr] = av.y;  As[lk + 2][lr] = av.z;  As[lk + 3][lr] = av.w;
    W1s[lk + 0][lr] = wv1.x; W1s[lk + 1][lr] = wv1.y; W1s[lk + 2][lr] = wv1.z; W1s[lk + 3][lr] = wv1.w;
    W2s[lk + 0][lr] = wv2.x; W2s[lk + 1][lr] = wv2.y; W2s[lk + 2][lr] = wv2.z; W2s[lk + 3][lr] = wv2.w;
    __syncthreads();
#pragma unroll
    for (int kk = 0; kk < 16; ++kk) {
      const float4 a = *reinterpret_cast<const float4*>(&As[kk][tm * 4]);
      const float4 uu4 = *reinterpret_cast<const float4*>(&W1s[kk][tn * 4]);
      const float4 vv4 = *reinterpret_cast<const float4*>(&W2s[kk][tn * 4]);
      const float aa[4] = {a.x, a.y, a.z, a.w};
      const float uu[4] = {uu4.x, uu4.y, uu4.z, uu4.w};
      const float vv[4] = {vv4.x, vv4.y, vv4.z, vv4.w};
#pragma unroll
      for (int mm = 0; mm < 4; ++mm)
#pragma unroll
        for (int nn = 0; nn < 4; ++nn) {
          ac1[mm][nn] += aa[mm] * uu[nn];
          ac2[mm][nn] += aa[mm] * vv[nn];
        }
    }
  }
#pragma unroll
  for (int mm = 0; mm < 4; ++mm) {
    const int row = m0 + tm * 4 + mm;
#pragma unroll
    for (int nn = 0; nn < 4; ++nn) {
      const int f = n0 + tn * 4 + nn;
      if (f < kF) {
        const float s1 = fmaxf(ac1[mm][nn] + bl1[f], 0.f);
        const float s2 = fmaxf(ac2[mm][nn] + bl2[f], 0.f);
        const float inv = 1.f / (s1 + s2 + 1e-16f);
        const float xv = x[(size_t)row * kF + f];
        o1[(size_t)row * kF + f] = s1 * inv * xv;
        o2[(size_t)row * kF + f] = s2 * inv * xv;
      }
    }
  }
}

// ---------------------------------------------------------------------------
extern "C" void kernel_launch(void* const* d_in, const int* in_sizes, int n_in,
                              void* d_out, int out_size, void* d_ws, size_t ws_size,
                              hipStream_t stream) {
  const float* x = (const float*)d_in[0];
  GruParams P;
  P.wih[0] = (const float*)d_in[1];  P.whh[0] = (const float*)d_in[2];
  P.bih[0] = (const float*)d_in[3];  P.bhh[0] = (const float*)d_in[4];
  P.wih[1] = (const float*)d_in[5];  P.whh[1] = (const float*)d_in[6];
  P.bih[1] = (const float*)d_in[7];  P.bhh[1] = (const float*)d_in[8];
  P.wih[2] = (const float*)d_in[9];  P.whh[2] = (const float*)d_in[10];
  P.bih[2] = (const float*)d_in[11]; P.bhh[2] = (const float*)d_in[12];
  const float* w_l1 = (const float*)d_in[13];
  const float* b_l1 = (const float*)d_in[14];
  const float* w_l2 = (const float*)d_in[15];
  const float* b_l2 = (const float*)d_in[16];

  // ws layout (round-1-proven ~66 MB footprint): xq | out_h | prog | lall
  float* xq = (float*)d_ws;                              // 8,404,992 floats
  float* out_h = xq + (size_t)kT * 8 * kF * 4;           // 8,388,608 floats
  int* prog = (int*)(out_h + (size_t)kB * kT * kH);      // 192 ints (pad 256)
  int* lall = prog + 256;                                // 3 x stride-32 ints
  P.xq = xq;
  P.out_h = out_h;
  P.prog = prog;
  P.lall = lall;

  // rings live in d_out's o1 region (12 MB of 33.6 MB; dead before out_mask
  // overwrites o1). o1/o2 are the final outputs.
  float* o1 = (float*)d_out;
  float* o2 = o1 + (size_t)kB * kT * kF;
  const size_t ringSz = (size_t)kD * kHSlot;             // 4 MB each
  for (int l = 0; l < 3; ++l) P.ring[l] = o1 + (size_t)l * ringSz;

  // zero prog + lall and slot 0 (= h(0) = 0) of each ring (every call)
  hipMemsetAsync(prog, 0, 512 * sizeof(int), stream);
  hipMemsetAsync(P.ring[0], 0, kHSlot * sizeof(float), stream);
  hipMemsetAsync(P.ring[1], 0, kHSlot * sizeof(float), stream);
  hipMemsetAsync(P.ring[2], 0, kHSlot * sizeof(float), stream);

  transpose_x<<<dim3(17, kT), 256, 0, stream>>>(x, xq);

  void* args[] = { (void*)&P };
  hipLaunchCooperativeKernel((void*)gru_seq, dim3(195), dim3(512), args, 0u, stream);

  out_mask<<<dim3(9, 256), 256, 0, stream>>>(out_h, w_l1, b_l1, w_l2, b_l2, x, o1, o2);
}